// Round 3
// baseline (562.505 us; speedup 1.0000x reference)
//
#include <hip/hip_runtime.h>
#include <hip/hip_fp16.h>
#include <math.h>
#include <float.h>
#include <stdint.h>

#define NN 100000
#define NE 1600000

#define SCAN_T 256
#define SCAN_E 1024
#define SCAN_NB ((NN + SCAN_E - 1) / SCAN_E)   // 98

#define NBUCK ((NN + 255) / 256)               // 391 buckets of 256 dsts
#define EPB   4096                              // edges per binning block
#define NBLK  ((NE + EPB - 1) / EPB)            // 391 binning blocks
#define HISTN (NBUCK * NBLK)                    // 152,881
#define GS_NB ((HISTN + SCAN_E - 1) / SCAN_E)   // 150
#define BCAP  5120                              // per-bucket LDS sort capacity

typedef __attribute__((ext_vector_type(8))) short short8v;
typedef __attribute__((ext_vector_type(4))) float float4v;

// ---------------- bf16 split helpers (RNE) ----------------
__device__ __forceinline__ unsigned short f32_to_bf16_rne(float f) {
    unsigned u = __float_as_uint(f);
    u += 0x7FFFu + ((u >> 16) & 1u);
    return (unsigned short)(u >> 16);
}
__device__ __forceinline__ float bf16_to_f32(unsigned short h) {
    return __uint_as_float(((unsigned)h) << 16);
}

// ---------------- W pre-split into MFMA B-fragment layout ----------------
template<int K, int OUT>
__global__ __launch_bounds__(256)
void prep_w(const float* __restrict__ Wq, const float* __restrict__ Wk,
            const float* __restrict__ Wv, const float* __restrict__ Ws,
            unsigned short* __restrict__ wsp) {
    constexpr int NKS  = (K + 31) / 32;
    constexpr int OUTT = 4 * OUT;
    constexpr int NCT  = OUTT / 16;
    int idx = blockIdx.x * 256 + threadIdx.x;
    if (idx >= NCT * NKS * 512) return;
    int j    = idx & 7;
    int lane = (idx >> 3) & 63;
    int cell = idx >> 9;            // ct*NKS + ks
    int ks   = cell % NKS;
    int ct   = cell / NKS;
    int g = lane >> 4, ln = lane & 15;
    int k = ks * 32 + g * 8 + j;
    int c = ct * 16 + ln;
    int mat = c / OUT, cm = c % OUT;
    const float* W = (mat == 0) ? Wq : (mat == 1) ? Wk : (mat == 2) ? Wv : Ws;
    float f = (k < K) ? W[(size_t)k * OUT + cm] : 0.f;
    unsigned short h = f32_to_bf16_rne(f);
    float resid = f - bf16_to_f32(h);
    wsp[(size_t)cell * 1024 + lane * 8 + j]       = h;
    wsp[(size_t)cell * 1024 + 512 + lane * 8 + j] = f32_to_bf16_rne(resid);
}

// ---------------- fused linear via bf16x3 MFMA ----------------
template<int K, int OUT, int CTSPLIT>
__global__ __launch_bounds__(256)
void gemm_qkvs(const float* __restrict__ x,
               const unsigned short* __restrict__ wsp,
               const float* __restrict__ bq, const float* __restrict__ bk,
               const float* __restrict__ bv, const float* __restrict__ bs,
               float* __restrict__ q, unsigned short* __restrict__ kv,
               float* __restrict__ outskip) {
    constexpr int NKS  = (K + 31) / 32;
    constexpr int OUTT = 4 * OUT;
    constexpr int NCT  = OUTT / 16;
    constexpr int CTPB = NCT / CTSPLIT;

    const int t    = threadIdx.x;
    const int lane = t & 63;
    const int wv   = t >> 6;
    const int g    = lane >> 4;
    const int ln   = lane & 15;
    const int rowbase = (blockIdx.x * 4 + wv) * 32;
    if (rowbase >= NN) return;    // no barriers in this kernel

    union F8 { short8v v; unsigned short s[8]; uint4 u4; };

    // ---- load + split A fragments: 2 row-tiles of 16, K along lane>>4 ----
    F8 ahi[2][NKS], alo[2][NKS];
#pragma unroll
    for (int rt = 0; rt < 2; ++rt) {
        int r = rowbase + rt * 16 + ln;
        if (r >= NN) r = NN - 1;                 // stores are guarded
        const float* rowp = x + (size_t)r * K;
#pragma unroll
        for (int ks = 0; ks < NKS; ++ks) {
            const int k0 = ks * 32 + g * 8;
            float xv[8];
            if (k0 + 8 <= K) {
                float4 p0 = *(const float4*)(rowp + k0);
                float4 p1 = *(const float4*)(rowp + k0 + 4);
                xv[0] = p0.x; xv[1] = p0.y; xv[2] = p0.z; xv[3] = p0.w;
                xv[4] = p1.x; xv[5] = p1.y; xv[6] = p1.z; xv[7] = p1.w;
            } else {
#pragma unroll
                for (int j = 0; j < 8; ++j) xv[j] = 0.f;   // K=8 zero-pad
            }
#pragma unroll
            for (int j = 0; j < 8; ++j) {
                unsigned short h = f32_to_bf16_rne(xv[j]);
                ahi[rt][ks].s[j] = h;
                alo[rt][ks].s[j] = f32_to_bf16_rne(xv[j] - bf16_to_f32(h));
            }
        }
    }

    const int ct0 = blockIdx.y * CTPB;
#pragma unroll 1
    for (int ct = ct0; ct < ct0 + CTPB; ++ct) {
        F8 bhi[NKS], blo[NKS];
        const unsigned short* wp = wsp + (size_t)(ct * NKS) * 1024 + lane * 8;
#pragma unroll
        for (int ks = 0; ks < NKS; ++ks) {
            bhi[ks].u4 = *(const uint4*)(wp + ks * 1024);
            blo[ks].u4 = *(const uint4*)(wp + ks * 1024 + 512);
        }

        const int cb  = ct * 16;
        const int mat = cb / OUT;                // wave-uniform
        const int cm  = (cb % OUT) + ln;
        const float* B = (mat == 0) ? bq : (mat == 1) ? bk : (mat == 2) ? bv : bs;
        const float bias = B[cm];
        float4v acc0 = {bias, bias, bias, bias};
        float4v acc1 = {bias, bias, bias, bias};
#pragma unroll
        for (int ks = 0; ks < NKS; ++ks) {
            acc0 = __builtin_amdgcn_mfma_f32_16x16x32_bf16(ahi[0][ks].v, blo[ks].v, acc0, 0, 0, 0);
            acc0 = __builtin_amdgcn_mfma_f32_16x16x32_bf16(alo[0][ks].v, bhi[ks].v, acc0, 0, 0, 0);
            acc0 = __builtin_amdgcn_mfma_f32_16x16x32_bf16(ahi[0][ks].v, bhi[ks].v, acc0, 0, 0, 0);
            acc1 = __builtin_amdgcn_mfma_f32_16x16x32_bf16(ahi[1][ks].v, blo[ks].v, acc1, 0, 0, 0);
            acc1 = __builtin_amdgcn_mfma_f32_16x16x32_bf16(alo[1][ks].v, bhi[ks].v, acc1, 0, 0, 0);
            acc1 = __builtin_amdgcn_mfma_f32_16x16x32_bf16(ahi[1][ks].v, bhi[ks].v, acc1, 0, 0, 0);
        }

        // ---- epilogue: D row = (lane>>4)*4 + reg, col = lane&15 (HW-verified) ----
        if (mat == 0 || mat == 3) {
            float* dst = (mat == 0) ? q : outskip;
#pragma unroll
            for (int rt = 0; rt < 2; ++rt) {
                float4v a = rt ? acc1 : acc0;
#pragma unroll
                for (int reg = 0; reg < 4; ++reg) {
                    int node = rowbase + rt * 16 + g * 4 + reg;
                    if (node < NN)
                        dst[(size_t)node * OUT + cm] = a[reg];
                }
            }
        } else {
            // interleaved kv: channel c -> (c>>2)*8 + (c&3) + (k?0:4)
            const int base = (mat == 1) ? 0 : 4;
            const int kvoff = ((cm >> 2) * 8) + (cm & 3) + base;
#pragma unroll
            for (int rt = 0; rt < 2; ++rt) {
                float4v a = rt ? acc1 : acc0;
#pragma unroll
                for (int reg = 0; reg < 4; ++reg) {
                    int node = rowbase + rt * 16 + g * 4 + reg;
                    float f = a[reg];
                    float other = __shfl_xor(f, 1);  // pair adjacent columns
                    if (node < NN && !(ln & 1)) {
                        unsigned lo16 = __half_as_ushort(__float2half_rn(f));
                        unsigned hi16 = __half_as_ushort(__float2half_rn(other));
                        *(unsigned*)(kv + (size_t)node * (2 * OUT) + kvoff)
                            = lo16 | (hi16 << 16);
                    }
                }
            }
        }
    }
}

// ---------------- deterministic radix partition by dst>>8 (unchanged) ----------------
__global__ __launch_bounds__(256)
void bin_count(const int* __restrict__ ei, int* __restrict__ hist) {
    __shared__ int h[NBUCK];
    const int t = threadIdx.x;
    for (int i = t; i < NBUCK; i += 256) h[i] = 0;
    __syncthreads();
    int e0 = blockIdx.x * EPB;
    int e1 = e0 + EPB < NE ? e0 + EPB : NE;
    for (int i = e0 + t; i < e1; i += 256)
        atomicAdd(&h[ei[NE + i] >> 8], 1);
    __syncthreads();
    for (int i = t; i < NBUCK; i += 256)
        hist[(size_t)i * NBLK + blockIdx.x] = h[i];
}

__global__ __launch_bounds__(SCAN_T)
void gscan1(int* __restrict__ a, int* __restrict__ bsums) {
    __shared__ int lds[SCAN_T];
    int t = threadIdx.x;
    int base = blockIdx.x * SCAN_E + t * 4;
    int vals[4];
    int s = 0;
#pragma unroll
    for (int j = 0; j < 4; ++j) {
        int idx = base + j;
        vals[j] = (idx < HISTN) ? a[idx] : 0;
        s += vals[j];
    }
    lds[t] = s;
    __syncthreads();
    for (int off = 1; off < SCAN_T; off <<= 1) {
        int xx = (t >= off) ? lds[t - off] : 0;
        __syncthreads();
        lds[t] += xx;
        __syncthreads();
    }
    int run = (t > 0) ? lds[t - 1] : 0;
    if (t == SCAN_T - 1) bsums[blockIdx.x] = lds[t];
#pragma unroll
    for (int j = 0; j < 4; ++j) {
        int idx = base + j;
        if (idx < HISTN) a[idx] = run;
        run += vals[j];
    }
}

__global__ __launch_bounds__(256)
void gscan2(int* __restrict__ bsums) {
    __shared__ int lds[256];
    int t = threadIdx.x;
    lds[t] = (t < GS_NB) ? bsums[t] : 0;
    __syncthreads();
    for (int off = 1; off < 256; off <<= 1) {
        int xx = (t >= off) ? lds[t - off] : 0;
        __syncthreads();
        lds[t] += xx;
        __syncthreads();
    }
    if (t < GS_NB) bsums[t] = (t > 0) ? lds[t - 1] : 0;
}

__global__ __launch_bounds__(256)
void gscan3(int* __restrict__ a, const int* __restrict__ bsums,
            int* __restrict__ bstart) {
    int i = blockIdx.x * 256 + threadIdx.x;
    if (i < HISTN) {
        int v = a[i] + bsums[i / SCAN_E];
        a[i] = v;
        if (i % NBLK == 0) bstart[i / NBLK] = v;
    }
    if (i == 0) bstart[NBUCK] = NE;
}

__global__ __launch_bounds__(256)
void bin_scatter(const int* __restrict__ ei, const int* __restrict__ hist,
                 unsigned* __restrict__ ebuf) {
    __shared__ int off[NBUCK];
    const int t = threadIdx.x;
    for (int i = t; i < NBUCK; i += 256)
        off[i] = hist[(size_t)i * NBLK + blockIdx.x];
    __syncthreads();
    int e0 = blockIdx.x * EPB;
    int e1 = e0 + EPB < NE ? e0 + EPB : NE;
    for (int i = e0 + t; i < e1; i += 256) {
        int src = ei[i];
        int dst = ei[NE + i];
        int b = dst >> 8;
        int p = atomicAdd(&off[b], 1);
        ebuf[p] = ((unsigned)(dst & 255) << 17) | (unsigned)src;
    }
}

__global__ __launch_bounds__(256)
void bucket_hist(const int* __restrict__ bstart,
                 const unsigned* __restrict__ ebuf,
                 int* __restrict__ counts) {
    __shared__ int h[256];
    const int b = blockIdx.x;
    const int t = threadIdx.x;
    h[t] = 0;
    __syncthreads();
    int beg = bstart[b], end = bstart[b + 1];
    for (int i = beg + t; i < end; i += 256)
        atomicAdd(&h[ebuf[i] >> 17], 1);
    __syncthreads();
    int d = b * 256 + t;
    if (d < NN) counts[d] = h[t];
}

__global__ __launch_bounds__(SCAN_T)
void scan1(const int* __restrict__ counts, int* __restrict__ offsets,
           int* __restrict__ blocksums) {
    __shared__ int lds[SCAN_T];
    int t = threadIdx.x;
    int base = blockIdx.x * SCAN_E + t * 4;
    int vals[4];
    int s = 0;
#pragma unroll
    for (int j = 0; j < 4; ++j) {
        int idx = base + j;
        vals[j] = (idx < NN) ? counts[idx] : 0;
        s += vals[j];
    }
    lds[t] = s;
    __syncthreads();
    for (int off = 1; off < SCAN_T; off <<= 1) {
        int xx = (t >= off) ? lds[t - off] : 0;
        __syncthreads();
        lds[t] += xx;
        __syncthreads();
    }
    int run = (t > 0) ? lds[t - 1] : 0;
    if (t == SCAN_T - 1) blocksums[blockIdx.x] = lds[t];
#pragma unroll
    for (int j = 0; j < 4; ++j) {
        int idx = base + j;
        if (idx < NN) offsets[idx] = run;
        run += vals[j];
    }
}

__global__ __launch_bounds__(128)
void scan2(int* __restrict__ blocksums) {
    __shared__ int lds[128];
    int t = threadIdx.x;
    lds[t] = (t < SCAN_NB) ? blocksums[t] : 0;
    __syncthreads();
    for (int off = 1; off < 128; off <<= 1) {
        int xx = (t >= off) ? lds[t - off] : 0;
        __syncthreads();
        lds[t] += xx;
        __syncthreads();
    }
    if (t < SCAN_NB) blocksums[t] = (t > 0) ? lds[t - 1] : 0;
}

__global__ __launch_bounds__(256)
void scan3(int* __restrict__ offsets, const int* __restrict__ blocksums) {
    int i = blockIdx.x * blockDim.x + threadIdx.x;
    if (i < NN) offsets[i] = offsets[i] + blocksums[i / SCAN_E];
    if (i == 0) offsets[NN] = NE;
}

__global__ __launch_bounds__(256)
void csr_write(const int* __restrict__ bstart,
               const unsigned* __restrict__ ebuf,
               const int* __restrict__ offsets,
               int* __restrict__ sorted_src) {
    __shared__ int h[256];
    __shared__ int pre[256];
    __shared__ int posi[256];
    __shared__ unsigned srt[BCAP];
    const int b = blockIdx.x;
    const int t = threadIdx.x;
    h[t] = 0;
    __syncthreads();
    int beg = bstart[b];
    int cnt = bstart[b + 1] - beg;
    cnt = cnt < BCAP ? cnt : BCAP;
    const unsigned* buf = ebuf + beg;
    for (int i = t; i < cnt; i += 256)
        atomicAdd(&h[buf[i] >> 17], 1);
    __syncthreads();
    int v = h[t];
    pre[t] = v;
    __syncthreads();
    for (int off = 1; off < 256; off <<= 1) {
        int xx = (t >= off) ? pre[t - off] : 0;
        __syncthreads();
        pre[t] += xx;
        __syncthreads();
    }
    posi[t] = pre[t] - v;
    __syncthreads();
    for (int i = t; i < cnt; i += 256) {
        unsigned u = buf[i];
        int dl = u >> 17;
        int p = atomicAdd(&posi[dl], 1);
        srt[p] = u & 0x1FFFFu;
    }
    __syncthreads();
    const int base = offsets[b << 8];
    for (int i = t; i < cnt; i += 256)
        sorted_src[base + i] = (int)srt[i];
}

// ---- 8-lane group sum: quad_perm xor1, xor2 (DPP), ds_swizzle xor4 ----
__device__ __forceinline__ float grp8_sum(float x) {
    int y;
    y = __builtin_amdgcn_update_dpp(0, __float_as_int(x), 0xB1, 0xF, 0xF, true); x += __int_as_float(y); // xor 1
    y = __builtin_amdgcn_update_dpp(0, __float_as_int(x), 0x4E, 0xF, 0xF, true); x += __int_as_float(y); // xor 2
    y = __builtin_amdgcn_ds_swizzle(__float_as_int(x), 0x101F);                  x += __int_as_float(y); // xor 4
    return x;
}

// dot-accumulate: acc += lo16(kk)*q0 + hi16(kk)*q1  (mix-fma friendly)
__device__ __forceinline__ float d2(float acc, unsigned kk, float q0, float q1) {
    float2 f = __half22float2(*(__half2*)&kk);
    acc = fmaf(f.x, q0, acc);
    return fmaf(f.y, q1, acc);
}
// a = a*al + w*v  for a packed half pair
__device__ __forceinline__ void upd2(float& a0, float& a1, unsigned vv, float al, float w) {
    float2 f = __half22float2(*(__half2*)&vv);
    a0 = fmaf(a0, al, w * f.x);
    a1 = fmaf(a1, al, w * f.y);
}

// ---------------- fused attention gather: 8-lane groups ----------------
// Each wave = one dst; 8 groups x 8 lanes; lane handles 8 channels (+8 hi).
// kv row interleaved per 4-ch group [k0..k3 v0..v3]; lane's 8 lo channels are
// 32 contiguous bytes (2x uint4), hi at +256 bytes.
template<int C, bool RELU>
__global__ __launch_bounds__(256)
void attn_gather(const int* __restrict__ offsets,
                 const int* __restrict__ sorted_src,
                 const float* __restrict__ q,
                 const unsigned short* __restrict__ kv,
                 float* __restrict__ out, float scale) {
    const int wid  = (int)((blockIdx.x * blockDim.x + threadIdx.x) >> 6);
    const int lane = threadIdx.x & 63;
    if (wid >= NN) return;
    const int grp = lane >> 3;
    const int sub = lane & 7;
    constexpr bool P2  = (C > 64);
    constexpr int NAV  = P2 ? 16 : 8;
    const bool hi = P2 && (sub < (C - 64) / 8);

    const int beg = offsets[wid], end = offsets[wid + 1];
    const float sl = scale * 1.44269504f;   // fold scale + log2(e) into q

    // ---- q channels [8sub,8sub+8) lo (+64 hi), pre-scaled ----
    const float* qrow = q + (size_t)wid * C + sub * 8;
    float qf[NAV];
    {
        float4 q0 = *(const float4*)(qrow);
        float4 q1 = *(const float4*)(qrow + 4);
        qf[0] = q0.x * sl; qf[1] = q0.y * sl; qf[2] = q0.z * sl; qf[3] = q0.w * sl;
        qf[4] = q1.x * sl; qf[5] = q1.y * sl; qf[6] = q1.z * sl; qf[7] = q1.w * sl;
        if (P2) {
#pragma unroll
            for (int j = 8; j < NAV; ++j) qf[j] = 0.f;
            if (hi) {
                float4 q2 = *(const float4*)(qrow + 64);
                float4 q3 = *(const float4*)(qrow + 68);
                qf[8]  = q2.x * sl; qf[9]  = q2.y * sl; qf[10] = q2.z * sl; qf[11] = q2.w * sl;
                qf[12] = q3.x * sl; qf[13] = q3.y * sl; qf[14] = q3.z * sl; qf[15] = q3.w * sl;
            }
        }
    }

    float m = -FLT_MAX, l = 0.f;
    float av[NAV];
#pragma unroll
    for (int j = 0; j < NAV; ++j) av[j] = 0.f;

    const uint4 zz = make_uint4(0, 0, 0, 0);
    uint4 A0 = zz, A1 = zz, A2 = zz, A3 = zz;
    uint4 B0 = zz, B1 = zz, B2 = zz, B3 = zz;

#define GLOAD(S0, S1, S2, S3, IDX)                                            \
    if ((IDX) < end) {                                                        \
        const unsigned short* row_ =                                          \
            kv + (size_t)sorted_src[IDX] * (2 * C) + 16 * sub;                \
        S0 = *(const uint4*)(row_);                                           \
        S1 = *(const uint4*)(row_ + 8);                                       \
        if (P2 && hi) {                                                       \
            S2 = *(const uint4*)(row_ + 128);                                 \
            S3 = *(const uint4*)(row_ + 136);                                 \
        }                                                                     \
    }

#define GCOMP(S0, S1, S2, S3)                                                 \
    {                                                                         \
        float part = 0.f;                                                     \
        part = d2(part, S0.x, qf[0], qf[1]);                                  \
        part = d2(part, S0.y, qf[2], qf[3]);                                  \
        part = d2(part, S1.x, qf[4], qf[5]);                                  \
        part = d2(part, S1.y, qf[6], qf[7]);                                  \
        if (P2) {                                                             \
            part = d2(part, S2.x, qf[8],  qf[9]);                             \
            part = d2(part, S2.y, qf[10], qf[11]);                            \
            part = d2(part, S3.x, qf[12], qf[13]);                            \
            part = d2(part, S3.y, qf[14], qf[15]);                            \
        }                                                                     \
        float s  = grp8_sum(part);                                            \
        float mn = fmaxf(m, s);                                               \
        float al = __builtin_amdgcn_exp2f(m - mn);                            \
        float w  = __builtin_amdgcn_exp2f(s - mn);                            \
        l = l * al + w;                                                       \
        upd2(av[0], av[1], S0.z, al, w);                                      \
        upd2(av[2], av[3], S0.w, al, w);                                      \
        upd2(av[4], av[5], S1.z, al, w);                                      \
        upd2(av[6], av[7], S1.w, al, w);                                      \
        if (P2) {                                                             \
            upd2(av[8],  av[9],  S2.z, al, w);                                \
            upd2(av[10], av[11], S2.w, al, w);                                \
            upd2(av[12], av[13], S3.z, al, w);                                \
            upd2(av[14], av[15], S3.w, al, w);                                \
        }                                                                     \
        m = mn;                                                               \
    }

    int i = beg + grp;
    GLOAD(A0, A1, A2, A3, i)
    GLOAD(B0, B1, B2, B3, i + 8)
    while (i < end) {
        GCOMP(A0, A1, A2, A3)
        GLOAD(A0, A1, A2, A3, i + 16)
        i += 8;
        if (i >= end) break;
        GCOMP(B0, B1, B2, B3)
        GLOAD(B0, B1, B2, B3, i + 16)
        i += 8;
    }
#undef GLOAD
#undef GCOMP

    // ---- merge the 8 groups: butterfly over lane-xor 8, 16, 32 ----
#pragma unroll
    for (int d = 8; d <= 32; d <<= 1) {
        float mo = __shfl_xor(m, d);
        float lo = __shfl_xor(l, d);
        float mn = fmaxf(m, mo);
        float e1 = (l  > 0.f) ? __builtin_amdgcn_exp2f(m  - mn) : 0.f;
        float e2 = (lo > 0.f) ? __builtin_amdgcn_exp2f(mo - mn) : 0.f;
        l = l * e1 + lo * e2;
#pragma unroll
        for (int j = 0; j < NAV; ++j) {
            float ao = __shfl_xor(av[j], d);
            av[j] = av[j] * e1 + ao * e2;
        }
        m = mn;
    }

    if (grp == 0) {
        float inv = (l > 0.f) ? 1.f / l : 0.f;
        size_t o = (size_t)wid * C + sub * 8;
        float4 s0 = *(const float4*)(out + o);
        float4 s1 = *(const float4*)(out + o + 4);
        float4 r0, r1;
        r0.x = s0.x + av[0] * inv; r0.y = s0.y + av[1] * inv;
        r0.z = s0.z + av[2] * inv; r0.w = s0.w + av[3] * inv;
        r1.x = s1.x + av[4] * inv; r1.y = s1.y + av[5] * inv;
        r1.z = s1.z + av[6] * inv; r1.w = s1.w + av[7] * inv;
        if (RELU) {
            r0.x = fmaxf(r0.x, 0.f); r0.y = fmaxf(r0.y, 0.f);
            r0.z = fmaxf(r0.z, 0.f); r0.w = fmaxf(r0.w, 0.f);
            r1.x = fmaxf(r1.x, 0.f); r1.y = fmaxf(r1.y, 0.f);
            r1.z = fmaxf(r1.z, 0.f); r1.w = fmaxf(r1.w, 0.f);
        }
        *(float4*)(out + o)     = r0;
        *(float4*)(out + o + 4) = r1;
        if (P2 && hi) {
            float4 s2 = *(const float4*)(out + o + 64);
            float4 s3 = *(const float4*)(out + o + 68);
            float4 r2, r3;
            r2.x = s2.x + av[8]  * inv; r2.y = s2.y + av[9]  * inv;
            r2.z = s2.z + av[10] * inv; r2.w = s2.w + av[11] * inv;
            r3.x = s3.x + av[12] * inv; r3.y = s3.y + av[13] * inv;
            r3.z = s3.z + av[14] * inv; r3.w = s3.w + av[15] * inv;
            if (RELU) {
                r2.x = fmaxf(r2.x, 0.f); r2.y = fmaxf(r2.y, 0.f);
                r2.z = fmaxf(r2.z, 0.f); r2.w = fmaxf(r2.w, 0.f);
                r3.x = fmaxf(r3.x, 0.f); r3.y = fmaxf(r3.y, 0.f);
                r3.z = fmaxf(r3.z, 0.f); r3.w = fmaxf(r3.w, 0.f);
            }
            *(float4*)(out + o + 64) = r2;
            *(float4*)(out + o + 68) = r3;
        }
    }
}

// ---------------- host side ----------------
template<int K, int OUT, bool RELU>
static void run_layer(const float* xin, const unsigned short* wsp,
                      const float* const* Wb,
                      const int* offsets, const int* sorted_src,
                      float* q, unsigned short* kv,
                      float* out, hipStream_t stream) {
    constexpr int CTSPLIT = 2;
    dim3 gg((NN + 127) / 128, CTSPLIT);
    gemm_qkvs<K, OUT, CTSPLIT><<<gg, 256, 0, stream>>>(
        xin, wsp, Wb[1], Wb[3], Wb[5], Wb[7], q, kv, out);

    float scale = 1.0f / sqrtf((float)OUT);
    attn_gather<OUT, RELU><<<(NN + 3) / 4, 256, 0, stream>>>(
        offsets, sorted_src, q, kv, out, scale);
}

extern "C" void kernel_launch(void* const* d_in, const int* in_sizes, int n_in,
                              void* d_out, int out_size, void* d_ws, size_t ws_size,
                              hipStream_t stream) {
    const float* x  = (const float*)d_in[0];
    const int*   ei = (const int*)d_in[1];
    const float* Wb0[8], *Wb1[8], *Wb2[8];
    for (int i = 0; i < 8; ++i) {
        Wb0[i] = (const float*)d_in[2 + i];
        Wb1[i] = (const float*)d_in[10 + i];
        Wb2[i] = (const float*)d_in[18 + i];
    }
    float* out = (float*)d_out;

    char* ws = (char*)d_ws;
    const size_t CMAX = 112;
    size_t off = 0;
    float*          q  = (float*)(ws + off);          off += (size_t)NN * CMAX * 4;
    unsigned short* kv = (unsigned short*)(ws + off); off += (size_t)NN * 2 * CMAX * 2;
    float* h0          = (float*)(ws + off);          off += (size_t)NN * 64 * 4;
    float* h1          = (float*)(ws + off);          off += (size_t)NN * 64 * 4;
    int*   sorted_src  = (int*)(ws + off);            off += (size_t)NE * 4;
    int*   counts      = (int*)(ws + off);            off += (size_t)NN * 4;
    int*   offsets     = (int*)(ws + off);            off += (size_t)(NN + 1) * 4;
    int*   blocksums   = (int*)(ws + off);            off += (size_t)SCAN_NB * 4;
    int*   hist        = (int*)(ws + off);            off += (size_t)HISTN * 4;
    int*   gsums       = (int*)(ws + off);            off += (size_t)GS_NB * 4;
    int*   bstart      = (int*)(ws + off);            off += (size_t)(NBUCK + 1) * 4;
    unsigned* ebuf     = (unsigned*)(ws + off);       off += (size_t)NE * 4;
    (void)ws_size; (void)in_sizes; (void)n_in; (void)out_size;

    // ---- build CSR once: deterministic radix partition + per-bucket LDS sort ----
    bin_count<<<NBLK, 256, 0, stream>>>(ei, hist);
    gscan1<<<GS_NB, SCAN_T, 0, stream>>>(hist, gsums);
    gscan2<<<1, 256, 0, stream>>>(gsums);
    gscan3<<<(HISTN + 255) / 256, 256, 0, stream>>>(hist, gsums, bstart);
    bin_scatter<<<NBLK, 256, 0, stream>>>(ei, hist, ebuf);
    bucket_hist<<<NBUCK, 256, 0, stream>>>(bstart, ebuf, counts);
    scan1<<<SCAN_NB, SCAN_T, 0, stream>>>(counts, offsets, blocksums);
    scan2<<<1, 128, 0, stream>>>(blocksums);
    scan3<<<(NN + 255) / 256, 256, 0, stream>>>(offsets, blocksums);
    csr_write<<<NBUCK, 256, 0, stream>>>(bstart, ebuf, offsets, sorted_src);

    // ---- W pre-split (aliased into ebuf; dead after csr_write, stream-ordered) ----
    unsigned short* wspbase =
        (unsigned short*)(((uintptr_t)ebuf + 255) & ~(uintptr_t)255);
    unsigned short* wsp0 = wspbase;                  // 16 ct * 1 ks * 1024
    unsigned short* wsp1 = wsp0 + 16 * 1 * 1024;     // 16 ct * 2 ks * 1024
    unsigned short* wsp2 = wsp1 + 16 * 2 * 1024;     // 28 ct * 2 ks * 1024
    prep_w<8, 64><<<(16 * 1 * 512 + 255) / 256, 256, 0, stream>>>(
        Wb0[0], Wb0[2], Wb0[4], Wb0[6], wsp0);
    prep_w<64, 64><<<(16 * 2 * 512 + 255) / 256, 256, 0, stream>>>(
        Wb1[0], Wb1[2], Wb1[4], Wb1[6], wsp1);
    prep_w<64, 112><<<(28 * 2 * 512 + 255) / 256, 256, 0, stream>>>(
        Wb2[0], Wb2[2], Wb2[4], Wb2[6], wsp2);

    run_layer<8,  64, true >(x,  wsp0, Wb0, offsets, sorted_src, q, kv, h0,  stream);
    run_layer<64, 64, true >(h0, wsp1, Wb1, offsets, sorted_src, q, kv, h1,  stream);
    run_layer<64, 112, false>(h1, wsp2, Wb2, offsets, sorted_src, q, kv, out, stream);
}

// Round 4
// 558.639 us; speedup vs baseline: 1.0069x; 1.0069x over previous
//
#include <hip/hip_runtime.h>
#include <hip/hip_fp16.h>
#include <math.h>
#include <float.h>
#include <stdint.h>

#define NN 100000
#define NE 1600000

#define SCAN_T 256
#define SCAN_E 1024
#define SCAN_NB ((NN + SCAN_E - 1) / SCAN_E)   // 98

#define NBUCK ((NN + 255) / 256)               // 391 buckets of 256 dsts
#define EPB   4096                              // edges per binning block
#define NBLK  ((NE + EPB - 1) / EPB)            // 391 binning blocks
#define HISTN (NBUCK * NBLK)                    // 152,881
#define GS_NB ((HISTN + SCAN_E - 1) / SCAN_E)   // 150
#define BCAP  5120                              // per-bucket LDS sort capacity

typedef __attribute__((ext_vector_type(8))) short short8v;
typedef __attribute__((ext_vector_type(4))) float float4v;

// ---------------- bf16 split helpers (RNE) ----------------
__device__ __forceinline__ unsigned short f32_to_bf16_rne(float f) {
    unsigned u = __float_as_uint(f);
    u += 0x7FFFu + ((u >> 16) & 1u);
    return (unsigned short)(u >> 16);
}
__device__ __forceinline__ float bf16_to_f32(unsigned short h) {
    return __uint_as_float(((unsigned)h) << 16);
}

// ---------------- W pre-split into MFMA B-fragment layout (single launch) ----
// layout: per (ct, ks) cell of 1024 ushort: [hi: 64 lanes x 8][lo: 64 lanes x 8]
// lane l of a wave holds B[k = ks*32 + (l>>4)*8 + j][col = ct*16 + (l&15)]
__device__ __forceinline__ void prep_one(int idx, int K, int OUT,
    const float* Wq, const float* Wk, const float* Wv, const float* Ws,
    unsigned short* wsp) {
    int NKS  = (K + 31) / 32;
    int j    = idx & 7;
    int lane = (idx >> 3) & 63;
    int cell = idx >> 9;            // ct*NKS + ks
    int ks   = cell % NKS;
    int ct   = cell / NKS;
    int g = lane >> 4, ln = lane & 15;
    int k = ks * 32 + g * 8 + j;
    int c = ct * 16 + ln;
    int mat = c / OUT, cm = c % OUT;
    const float* W = (mat == 0) ? Wq : (mat == 1) ? Wk : (mat == 2) ? Wv : Ws;
    float f = (k < K) ? W[(size_t)k * OUT + cm] : 0.f;
    unsigned short h = f32_to_bf16_rne(f);
    float resid = f - bf16_to_f32(h);
    wsp[(size_t)cell * 1024 + lane * 8 + j]       = h;
    wsp[(size_t)cell * 1024 + 512 + lane * 8 + j] = f32_to_bf16_rne(resid);
}

#define PREP_N0 (16 * 1 * 512)   // 8192
#define PREP_N1 (16 * 2 * 512)   // 16384
#define PREP_N2 (28 * 2 * 512)   // 28672
#define PREP_NT (PREP_N0 + PREP_N1 + PREP_N2)

__global__ __launch_bounds__(256)
void prep_w_all(const float* __restrict__ q0W, const float* __restrict__ k0W,
                const float* __restrict__ v0W, const float* __restrict__ s0W,
                const float* __restrict__ q1W, const float* __restrict__ k1W,
                const float* __restrict__ v1W, const float* __restrict__ s1W,
                const float* __restrict__ q2W, const float* __restrict__ k2W,
                const float* __restrict__ v2W, const float* __restrict__ s2W,
                unsigned short* __restrict__ wsp0,
                unsigned short* __restrict__ wsp1,
                unsigned short* __restrict__ wsp2) {
    int idx = blockIdx.x * 256 + threadIdx.x;
    if (idx < PREP_N0)
        prep_one(idx, 8, 64, q0W, k0W, v0W, s0W, wsp0);
    else if (idx < PREP_N0 + PREP_N1)
        prep_one(idx - PREP_N0, 64, 64, q1W, k1W, v1W, s1W, wsp1);
    else if (idx < PREP_NT)
        prep_one(idx - PREP_N0 - PREP_N1, 64, 112, q2W, k2W, v2W, s2W, wsp2);
}

// ---------------- fused linear via bf16x3 MFMA ----------------
// Y[N x 4*OUT] = X[N x K] @ [Wq|Wk|Wv|Ws] + bias, routed to q (f32), kv (f16
// packed, INTERLEAVED: per 4-channel group [k0..k3 v0..v3]), outskip (f32).
template<int K, int OUT, int CTSPLIT>
__global__ __launch_bounds__(256)
void gemm_qkvs(const float* __restrict__ x,
               const unsigned short* __restrict__ wsp,
               const float* __restrict__ bq, const float* __restrict__ bk,
               const float* __restrict__ bv, const float* __restrict__ bs,
               float* __restrict__ q, unsigned short* __restrict__ kv,
               float* __restrict__ outskip) {
    constexpr int NKS  = (K + 31) / 32;
    constexpr int OUTT = 4 * OUT;
    constexpr int NCT  = OUTT / 16;
    constexpr int CTPB = NCT / CTSPLIT;

    const int t    = threadIdx.x;
    const int lane = t & 63;
    const int wv   = t >> 6;
    const int g    = lane >> 4;
    const int ln   = lane & 15;
    const int rowbase = (blockIdx.x * 4 + wv) * 32;
    if (rowbase >= NN) return;    // no barriers in this kernel

    union F8 { short8v v; unsigned short s[8]; uint4 u4; };

    // ---- load + split A fragments: 2 row-tiles of 16, K along lane>>4 ----
    F8 ahi[2][NKS], alo[2][NKS];
#pragma unroll
    for (int rt = 0; rt < 2; ++rt) {
        int r = rowbase + rt * 16 + ln;
        if (r >= NN) r = NN - 1;                 // stores are guarded
        const float* rowp = x + (size_t)r * K;
#pragma unroll
        for (int ks = 0; ks < NKS; ++ks) {
            const int k0 = ks * 32 + g * 8;
            float xv[8];
            if (k0 + 8 <= K) {
                float4 p0 = *(const float4*)(rowp + k0);
                float4 p1 = *(const float4*)(rowp + k0 + 4);
                xv[0] = p0.x; xv[1] = p0.y; xv[2] = p0.z; xv[3] = p0.w;
                xv[4] = p1.x; xv[5] = p1.y; xv[6] = p1.z; xv[7] = p1.w;
            } else {
#pragma unroll
                for (int j = 0; j < 8; ++j) xv[j] = 0.f;   // K=8 zero-pad
            }
#pragma unroll
            for (int j = 0; j < 8; ++j) {
                unsigned short h = f32_to_bf16_rne(xv[j]);
                ahi[rt][ks].s[j] = h;
                alo[rt][ks].s[j] = f32_to_bf16_rne(xv[j] - bf16_to_f32(h));
            }
        }
    }

    const int ct0 = blockIdx.y * CTPB;
#pragma unroll 1
    for (int ct = ct0; ct < ct0 + CTPB; ++ct) {
        F8 bhi[NKS], blo[NKS];
        const unsigned short* wp = wsp + (size_t)(ct * NKS) * 1024 + lane * 8;
#pragma unroll
        for (int ks = 0; ks < NKS; ++ks) {
            bhi[ks].u4 = *(const uint4*)(wp + ks * 1024);
            blo[ks].u4 = *(const uint4*)(wp + ks * 1024 + 512);
        }

        const int cb  = ct * 16;
        const int mat = cb / OUT;                // wave-uniform
        const int cm  = (cb % OUT) + ln;
        const float* B = (mat == 0) ? bq : (mat == 1) ? bk : (mat == 2) ? bv : bs;
        const float bias = B[cm];
        float4v acc0 = {bias, bias, bias, bias};
        float4v acc1 = {bias, bias, bias, bias};
#pragma unroll
        for (int ks = 0; ks < NKS; ++ks) {
            acc0 = __builtin_amdgcn_mfma_f32_16x16x32_bf16(ahi[0][ks].v, blo[ks].v, acc0, 0, 0, 0);
            acc0 = __builtin_amdgcn_mfma_f32_16x16x32_bf16(alo[0][ks].v, bhi[ks].v, acc0, 0, 0, 0);
            acc0 = __builtin_amdgcn_mfma_f32_16x16x32_bf16(ahi[0][ks].v, bhi[ks].v, acc0, 0, 0, 0);
            acc1 = __builtin_amdgcn_mfma_f32_16x16x32_bf16(ahi[1][ks].v, blo[ks].v, acc1, 0, 0, 0);
            acc1 = __builtin_amdgcn_mfma_f32_16x16x32_bf16(alo[1][ks].v, bhi[ks].v, acc1, 0, 0, 0);
            acc1 = __builtin_amdgcn_mfma_f32_16x16x32_bf16(ahi[1][ks].v, bhi[ks].v, acc1, 0, 0, 0);
        }

        // ---- epilogue: D row = (lane>>4)*4 + reg, col = lane&15 (HW-verified) ----
        if (mat == 0 || mat == 3) {
            float* dst = (mat == 0) ? q : outskip;
#pragma unroll
            for (int rt = 0; rt < 2; ++rt) {
                float4v a = rt ? acc1 : acc0;
#pragma unroll
                for (int reg = 0; reg < 4; ++reg) {
                    int node = rowbase + rt * 16 + g * 4 + reg;
                    if (node < NN)
                        dst[(size_t)node * OUT + cm] = a[reg];
                }
            }
        } else {
            // interleaved kv: channel c -> (c>>2)*8 + (c&3) + (k?0:4)
            const int base = (mat == 1) ? 0 : 4;
            const int kvoff = ((cm >> 2) * 8) + (cm & 3) + base;
#pragma unroll
            for (int rt = 0; rt < 2; ++rt) {
                float4v a = rt ? acc1 : acc0;
#pragma unroll
                for (int reg = 0; reg < 4; ++reg) {
                    int node = rowbase + rt * 16 + g * 4 + reg;
                    float f = a[reg];
                    float other = __shfl_xor(f, 1);  // pair adjacent columns
                    if (node < NN && !(ln & 1)) {
                        unsigned lo16 = __half_as_ushort(__float2half_rn(f));
                        unsigned hi16 = __half_as_ushort(__float2half_rn(other));
                        *(unsigned*)(kv + (size_t)node * (2 * OUT) + kvoff)
                            = lo16 | (hi16 << 16);
                    }
                }
            }
        }
    }
}

// ---------------- deterministic radix partition by dst>>8 (unchanged) ----------------
__global__ __launch_bounds__(256)
void bin_count(const int* __restrict__ ei, int* __restrict__ hist) {
    __shared__ int h[NBUCK];
    const int t = threadIdx.x;
    for (int i = t; i < NBUCK; i += 256) h[i] = 0;
    __syncthreads();
    int e0 = blockIdx.x * EPB;
    int e1 = e0 + EPB < NE ? e0 + EPB : NE;
    for (int i = e0 + t; i < e1; i += 256)
        atomicAdd(&h[ei[NE + i] >> 8], 1);
    __syncthreads();
    for (int i = t; i < NBUCK; i += 256)
        hist[(size_t)i * NBLK + blockIdx.x] = h[i];
}

__global__ __launch_bounds__(SCAN_T)
void gscan1(int* __restrict__ a, int* __restrict__ bsums) {
    __shared__ int lds[SCAN_T];
    int t = threadIdx.x;
    int base = blockIdx.x * SCAN_E + t * 4;
    int vals[4];
    int s = 0;
#pragma unroll
    for (int j = 0; j < 4; ++j) {
        int idx = base + j;
        vals[j] = (idx < HISTN) ? a[idx] : 0;
        s += vals[j];
    }
    lds[t] = s;
    __syncthreads();
    for (int off = 1; off < SCAN_T; off <<= 1) {
        int xx = (t >= off) ? lds[t - off] : 0;
        __syncthreads();
        lds[t] += xx;
        __syncthreads();
    }
    int run = (t > 0) ? lds[t - 1] : 0;
    if (t == SCAN_T - 1) bsums[blockIdx.x] = lds[t];
#pragma unroll
    for (int j = 0; j < 4; ++j) {
        int idx = base + j;
        if (idx < HISTN) a[idx] = run;
        run += vals[j];
    }
}

__global__ __launch_bounds__(256)
void gscan2(int* __restrict__ bsums) {
    __shared__ int lds[256];
    int t = threadIdx.x;
    lds[t] = (t < GS_NB) ? bsums[t] : 0;
    __syncthreads();
    for (int off = 1; off < 256; off <<= 1) {
        int xx = (t >= off) ? lds[t - off] : 0;
        __syncthreads();
        lds[t] += xx;
        __syncthreads();
    }
    if (t < GS_NB) bsums[t] = (t > 0) ? lds[t - 1] : 0;
}

__global__ __launch_bounds__(256)
void gscan3(int* __restrict__ a, const int* __restrict__ bsums,
            int* __restrict__ bstart) {
    int i = blockIdx.x * 256 + threadIdx.x;
    if (i < HISTN) {
        int v = a[i] + bsums[i / SCAN_E];
        a[i] = v;
        if (i % NBLK == 0) bstart[i / NBLK] = v;
    }
    if (i == 0) bstart[NBUCK] = NE;
}

__global__ __launch_bounds__(256)
void bin_scatter(const int* __restrict__ ei, const int* __restrict__ hist,
                 unsigned* __restrict__ ebuf) {
    __shared__ int off[NBUCK];
    const int t = threadIdx.x;
    for (int i = t; i < NBUCK; i += 256)
        off[i] = hist[(size_t)i * NBLK + blockIdx.x];
    __syncthreads();
    int e0 = blockIdx.x * EPB;
    int e1 = e0 + EPB < NE ? e0 + EPB : NE;
    for (int i = e0 + t; i < e1; i += 256) {
        int src = ei[i];
        int dst = ei[NE + i];
        int b = dst >> 8;
        int p = atomicAdd(&off[b], 1);
        ebuf[p] = ((unsigned)(dst & 255) << 17) | (unsigned)src;
    }
}

__global__ __launch_bounds__(256)
void bucket_hist(const int* __restrict__ bstart,
                 const unsigned* __restrict__ ebuf,
                 int* __restrict__ counts) {
    __shared__ int h[256];
    const int b = blockIdx.x;
    const int t = threadIdx.x;
    h[t] = 0;
    __syncthreads();
    int beg = bstart[b], end = bstart[b + 1];
    for (int i = beg + t; i < end; i += 256)
        atomicAdd(&h[ebuf[i] >> 17], 1);
    __syncthreads();
    int d = b * 256 + t;
    if (d < NN) counts[d] = h[t];
}

__global__ __launch_bounds__(SCAN_T)
void scan1(const int* __restrict__ counts, int* __restrict__ offsets,
           int* __restrict__ blocksums) {
    __shared__ int lds[SCAN_T];
    int t = threadIdx.x;
    int base = blockIdx.x * SCAN_E + t * 4;
    int vals[4];
    int s = 0;
#pragma unroll
    for (int j = 0; j < 4; ++j) {
        int idx = base + j;
        vals[j] = (idx < NN) ? counts[idx] : 0;
        s += vals[j];
    }
    lds[t] = s;
    __syncthreads();
    for (int off = 1; off < SCAN_T; off <<= 1) {
        int xx = (t >= off) ? lds[t - off] : 0;
        __syncthreads();
        lds[t] += xx;
        __syncthreads();
    }
    int run = (t > 0) ? lds[t - 1] : 0;
    if (t == SCAN_T - 1) blocksums[blockIdx.x] = lds[t];
#pragma unroll
    for (int j = 0; j < 4; ++j) {
        int idx = base + j;
        if (idx < NN) offsets[idx] = run;
        run += vals[j];
    }
}

__global__ __launch_bounds__(128)
void scan2(int* __restrict__ blocksums) {
    __shared__ int lds[128];
    int t = threadIdx.x;
    lds[t] = (t < SCAN_NB) ? blocksums[t] : 0;
    __syncthreads();
    for (int off = 1; off < 128; off <<= 1) {
        int xx = (t >= off) ? lds[t - off] : 0;
        __syncthreads();
        lds[t] += xx;
        __syncthreads();
    }
    if (t < SCAN_NB) blocksums[t] = (t > 0) ? lds[t - 1] : 0;
}

__global__ __launch_bounds__(256)
void scan3(int* __restrict__ offsets, const int* __restrict__ blocksums) {
    int i = blockIdx.x * blockDim.x + threadIdx.x;
    if (i < NN) offsets[i] = offsets[i] + blocksums[i / SCAN_E];
    if (i == 0) offsets[NN] = NE;
}

__global__ __launch_bounds__(256)
void csr_write(const int* __restrict__ bstart,
               const unsigned* __restrict__ ebuf,
               const int* __restrict__ offsets,
               int* __restrict__ sorted_src) {
    __shared__ int h[256];
    __shared__ int pre[256];
    __shared__ int posi[256];
    __shared__ unsigned srt[BCAP];
    const int b = blockIdx.x;
    const int t = threadIdx.x;
    h[t] = 0;
    __syncthreads();
    int beg = bstart[b];
    int cnt = bstart[b + 1] - beg;
    cnt = cnt < BCAP ? cnt : BCAP;
    const unsigned* buf = ebuf + beg;
    for (int i = t; i < cnt; i += 256)
        atomicAdd(&h[buf[i] >> 17], 1);
    __syncthreads();
    int v = h[t];
    pre[t] = v;
    __syncthreads();
    for (int off = 1; off < 256; off <<= 1) {
        int xx = (t >= off) ? pre[t - off] : 0;
        __syncthreads();
        pre[t] += xx;
        __syncthreads();
    }
    posi[t] = pre[t] - v;
    __syncthreads();
    for (int i = t; i < cnt; i += 256) {
        unsigned u = buf[i];
        int dl = u >> 17;
        int p = atomicAdd(&posi[dl], 1);
        srt[p] = u & 0x1FFFFu;
    }
    __syncthreads();
    const int base = offsets[b << 8];
    for (int i = t; i < cnt; i += 256)
        sorted_src[base + i] = (int)srt[i];
}

// ---- 16-lane row sum via DPP rotates (VALU pipe, no LDS) ----
__device__ __forceinline__ float row16_sum(float x) {
    int y;
    y = __builtin_amdgcn_update_dpp(0, __float_as_int(x), 0x121, 0xF, 0xF, true); x += __int_as_float(y);
    y = __builtin_amdgcn_update_dpp(0, __float_as_int(x), 0x122, 0xF, 0xF, true); x += __int_as_float(y);
    y = __builtin_amdgcn_update_dpp(0, __float_as_int(x), 0x124, 0xF, 0xF, true); x += __int_as_float(y);
    y = __builtin_amdgcn_update_dpp(0, __float_as_int(x), 0x128, 0xF, 0xF, true); x += __int_as_float(y);
    return x;
}

__device__ __forceinline__ float4 h4_to_f4(unsigned wx, unsigned wy) {
    union { unsigned u; __half2 h; } a, b;
    a.u = wx; b.u = wy;
    float2 f0 = __half22float2(a.h);
    float2 f1 = __half22float2(b.h);
    return make_float4(f0.x, f0.y, f1.x, f1.y);
}

// ---------------- fused attention gather (R1 16-lane structure) ----------------
// interleaved kv + rotating prefetch (DEPTH=4 for C<=64, 2 for C=112) + exp2
template<int C, bool RELU>
__global__ __launch_bounds__(256)
void attn_gather(const int* __restrict__ offsets,
                 const int* __restrict__ sorted_src,
                 const float* __restrict__ q,
                 const unsigned short* __restrict__ kv,
                 float* __restrict__ out, float scale) {
    const int wid  = (int)((blockIdx.x * blockDim.x + threadIdx.x) >> 6);
    const int lane = threadIdx.x & 63;
    if (wid >= NN) return;
    const int grp = lane >> 4;
    const int ch  = (lane & 15) * 4;
    constexpr bool P2 = (C > 64);
    constexpr int DEPTH = P2 ? 2 : 4;      // loads-in-flight per lane equalized
    const bool hi = P2 && (ch + 64 < C);

    const int beg = offsets[wid], end = offsets[wid + 1];

    const float sl = scale * 1.44269504f;   // fold scale + log2(e) into q
    float4 qv0 = *(const float4*)(q + (size_t)wid * C + ch);
    qv0.x *= sl; qv0.y *= sl; qv0.z *= sl; qv0.w *= sl;
    float4 qv1 = make_float4(0.f, 0.f, 0.f, 0.f);
    if (hi) {
        qv1 = *(const float4*)(q + (size_t)wid * C + ch + 64);
        qv1.x *= sl; qv1.y *= sl; qv1.z *= sl; qv1.w *= sl;
    }

    float m = -FLT_MAX, l = 0.f;
    float4 a0 = make_float4(0.f, 0.f, 0.f, 0.f);
    float4 a1 = make_float4(0.f, 0.f, 0.f, 0.f);

    const uint4 zz = make_uint4(0, 0, 0, 0);
    uint4 s0[DEPTH], s1[DEPTH];
#pragma unroll
    for (int d = 0; d < DEPTH; ++d) { s0[d] = zz; s1[d] = zz; }

    int i = beg + grp;
#pragma unroll
    for (int d = 0; d < DEPTH; ++d) {
        int idx = i + 4 * d;
        if (idx < end) {
            const unsigned short* row = kv + (size_t)sorted_src[idx] * (2 * C) + 2 * ch;
            s0[d] = *(const uint4*)(row);
            if (hi) s1[d] = *(const uint4*)(row + 128);
        }
    }

    while (i < end) {
#pragma unroll
        for (int d = 0; d < DEPTH; ++d) {
            // uint4 = [k0 k1 | k2 k3 | v0 v1 | v2 v3] halves, channels ch..ch+3
            float4 kf0 = h4_to_f4(s0[d].x, s0[d].y);
            float4 vf0 = h4_to_f4(s0[d].z, s0[d].w);
            float part = qv0.x * kf0.x + qv0.y * kf0.y + qv0.z * kf0.z + qv0.w * kf0.w;
            float4 vf1 = make_float4(0.f, 0.f, 0.f, 0.f);
            if (P2) {
                float4 kf1 = h4_to_f4(s1[d].x, s1[d].y);
                vf1 = h4_to_f4(s1[d].z, s1[d].w);
                part += qv1.x * kf1.x + qv1.y * kf1.y + qv1.z * kf1.z + qv1.w * kf1.w;
            }
            float s = row16_sum(part);                 // log2-domain score
            float mn = fmaxf(m, s);
            float al = __builtin_amdgcn_exp2f(m - mn);
            float w  = __builtin_amdgcn_exp2f(s - mn);
            l = l * al + w;
            a0.x = a0.x * al + w * vf0.x; a0.y = a0.y * al + w * vf0.y;
            a0.z = a0.z * al + w * vf0.z; a0.w = a0.w * al + w * vf0.w;
            if (P2) {
                a1.x = a1.x * al + w * vf1.x; a1.y = a1.y * al + w * vf1.y;
                a1.z = a1.z * al + w * vf1.z; a1.w = a1.w * al + w * vf1.w;
            }
            m = mn;
            int idn = i + 4 * DEPTH;                   // refill freed slot
            if (idn < end) {
                const unsigned short* row = kv + (size_t)sorted_src[idn] * (2 * C) + 2 * ch;
                s0[d] = *(const uint4*)(row);
                if (hi) s1[d] = *(const uint4*)(row + 128);
            }
            i += 4;
            if (i >= end) break;
        }
    }

    // merge the 4 groups: butterfly over lane-xor 16, 32
#pragma unroll
    for (int d = 16; d <= 32; d <<= 1) {
        float mo = __shfl_xor(m, d);
        float lo = __shfl_xor(l, d);
        float4 ao0, ao1;
        ao0.x = __shfl_xor(a0.x, d); ao0.y = __shfl_xor(a0.y, d);
        ao0.z = __shfl_xor(a0.z, d); ao0.w = __shfl_xor(a0.w, d);
        if (P2) {
            ao1.x = __shfl_xor(a1.x, d); ao1.y = __shfl_xor(a1.y, d);
            ao1.z = __shfl_xor(a1.z, d); ao1.w = __shfl_xor(a1.w, d);
        }
        float mn = fmaxf(m, mo);
        float e1 = (l  > 0.f) ? __builtin_amdgcn_exp2f(m  - mn) : 0.f;
        float e2 = (lo > 0.f) ? __builtin_amdgcn_exp2f(mo - mn) : 0.f;
        l = l * e1 + lo * e2;
        a0.x = a0.x * e1 + ao0.x * e2; a0.y = a0.y * e1 + ao0.y * e2;
        a0.z = a0.z * e1 + ao0.z * e2; a0.w = a0.w * e1 + ao0.w * e2;
        if (P2) {
            a1.x = a1.x * e1 + ao1.x * e2; a1.y = a1.y * e1 + ao1.y * e2;
            a1.z = a1.z * e1 + ao1.z * e2; a1.w = a1.w * e1 + ao1.w * e2;
        }
        m = mn;
    }

    if (lane < 16) {
        float inv = (l > 0.f) ? 1.f / l : 0.f;
        size_t o = (size_t)wid * C + ch;
        float4 sk = *(const float4*)(out + o);
        float4 r;
        r.x = sk.x + a0.x * inv; r.y = sk.y + a0.y * inv;
        r.z = sk.z + a0.z * inv; r.w = sk.w + a0.w * inv;
        if (RELU) {
            r.x = fmaxf(r.x, 0.f); r.y = fmaxf(r.y, 0.f);
            r.z = fmaxf(r.z, 0.f); r.w = fmaxf(r.w, 0.f);
        }
        *(float4*)(out + o) = r;
        if (hi) {
            float4 sk1 = *(const float4*)(out + o + 64);
            float4 r1;
            r1.x = sk1.x + a1.x * inv; r1.y = sk1.y + a1.y * inv;
            r1.z = sk1.z + a1.z * inv; r1.w = sk1.w + a1.w * inv;
            if (RELU) {
                r1.x = fmaxf(r1.x, 0.f); r1.y = fmaxf(r1.y, 0.f);
                r1.z = fmaxf(r1.z, 0.f); r1.w = fmaxf(r1.w, 0.f);
            }
            *(float4*)(out + o + 64) = r1;
        }
    }
}

// ---------------- host side ----------------
template<int K, int OUT, bool RELU>
static void run_layer(const float* xin, const unsigned short* wsp,
                      const float* const* Wb,
                      const int* offsets, const int* sorted_src,
                      float* q, unsigned short* kv,
                      float* out, hipStream_t stream) {
    constexpr int CTSPLIT = 2;
    dim3 gg((NN + 127) / 128, CTSPLIT);
    gemm_qkvs<K, OUT, CTSPLIT><<<gg, 256, 0, stream>>>(
        xin, wsp, Wb[1], Wb[3], Wb[5], Wb[7], q, kv, out);

    float scale = 1.0f / sqrtf((float)OUT);
    attn_gather<OUT, RELU><<<(NN + 3) / 4, 256, 0, stream>>>(
        offsets, sorted_src, q, kv, out, scale);
}

extern "C" void kernel_launch(void* const* d_in, const int* in_sizes, int n_in,
                              void* d_out, int out_size, void* d_ws, size_t ws_size,
                              hipStream_t stream) {
    const float* x  = (const float*)d_in[0];
    const int*   ei = (const int*)d_in[1];
    const float* Wb0[8], *Wb1[8], *Wb2[8];
    for (int i = 0; i < 8; ++i) {
        Wb0[i] = (const float*)d_in[2 + i];
        Wb1[i] = (const float*)d_in[10 + i];
        Wb2[i] = (const float*)d_in[18 + i];
    }
    float* out = (float*)d_out;

    char* ws = (char*)d_ws;
    const size_t CMAX = 112;
    size_t off = 0;
    float*          q  = (float*)(ws + off);          off += (size_t)NN * CMAX * 4;
    unsigned short* kv = (unsigned short*)(ws + off); off += (size_t)NN * 2 * CMAX * 2;
    float* h0          = (float*)(ws + off);          off += (size_t)NN * 64 * 4;
    float* h1          = (float*)(ws + off);          off += (size_t)NN * 64 * 4;
    int*   sorted_src  = (int*)(ws + off);            off += (size_t)NE * 4;
    int*   counts      = (int*)(ws + off);            off += (size_t)NN * 4;
    int*   offsets     = (int*)(ws + off);            off += (size_t)(NN + 1) * 4;
    int*   blocksums   = (int*)(ws + off);            off += (size_t)SCAN_NB * 4;
    int*   hist        = (int*)(ws + off);            off += (size_t)HISTN * 4;
    int*   gsums       = (int*)(ws + off);            off += (size_t)GS_NB * 4;
    int*   bstart      = (int*)(ws + off);            off += (size_t)(NBUCK + 1) * 4;
    unsigned* ebuf     = (unsigned*)(ws + off);       off += (size_t)NE * 4;
    (void)ws_size; (void)in_sizes; (void)n_in; (void)out_size;

    // ---- build CSR once: deterministic radix partition + per-bucket LDS sort ----
    bin_count<<<NBLK, 256, 0, stream>>>(ei, hist);
    gscan1<<<GS_NB, SCAN_T, 0, stream>>>(hist, gsums);
    gscan2<<<1, 256, 0, stream>>>(gsums);
    gscan3<<<(HISTN + 255) / 256, 256, 0, stream>>>(hist, gsums, bstart);
    bin_scatter<<<NBLK, 256, 0, stream>>>(ei, hist, ebuf);
    bucket_hist<<<NBUCK, 256, 0, stream>>>(bstart, ebuf, counts);
    scan1<<<SCAN_NB, SCAN_T, 0, stream>>>(counts, offsets, blocksums);
    scan2<<<1, 128, 0, stream>>>(blocksums);
    scan3<<<(NN + 255) / 256, 256, 0, stream>>>(offsets, blocksums);
    csr_write<<<NBUCK, 256, 0, stream>>>(bstart, ebuf, offsets, sorted_src);

    // ---- W pre-split (aliased into ebuf; dead after csr_write, stream-ordered) ----
    unsigned short* wspbase =
        (unsigned short*)(((uintptr_t)ebuf + 255) & ~(uintptr_t)255);
    unsigned short* wsp0 = wspbase;                  // 16 ct * 1 ks * 1024
    unsigned short* wsp1 = wsp0 + 16 * 1 * 1024;     // 16 ct * 2 ks * 1024
    unsigned short* wsp2 = wsp1 + 16 * 2 * 1024;     // 28 ct * 2 ks * 1024
    prep_w_all<<<(PREP_NT + 255) / 256, 256, 0, stream>>>(
        Wb0[0], Wb0[2], Wb0[4], Wb0[6],
        Wb1[0], Wb1[2], Wb1[4], Wb1[6],
        Wb2[0], Wb2[2], Wb2[4], Wb2[6],
        wsp0, wsp1, wsp2);

    run_layer<8,  64, true >(x,  wsp0, Wb0, offsets, sorted_src, q, kv, h0,  stream);
    run_layer<64, 64, true >(h0, wsp1, Wb1, offsets, sorted_src, q, kv, h1,  stream);
    run_layer<64, 112, false>(h1, wsp2, Wb2, offsets, sorted_src, q, kv, out, stream);
}

// Round 6
// 545.192 us; speedup vs baseline: 1.0318x; 1.0247x over previous
//
#include <hip/hip_runtime.h>
#include <hip/hip_fp16.h>
#include <math.h>
#include <float.h>
#include <stdint.h>

#define NN 100000
#define NE 1600000

#define SCAN_T 256
#define SCAN_E 1024
#define SCAN_NB ((NN + SCAN_E - 1) / SCAN_E)   // 98

#define NBUCK ((NN + 255) / 256)               // 391 buckets of 256 dsts
#define EPB   4096                              // edges per binning block
#define NBLK  ((NE + EPB - 1) / EPB)            // 391 binning blocks
#define HISTN (NBUCK * NBLK)                    // 152,881
#define GS_NB ((HISTN + SCAN_E - 1) / SCAN_E)   // 150
#define BCAP  5120                              // per-bucket LDS sort capacity

typedef __attribute__((ext_vector_type(8))) short short8v;
typedef __attribute__((ext_vector_type(4))) float float4v;

// ---------------- bf16 split helpers (RNE) ----------------
__device__ __forceinline__ unsigned short f32_to_bf16_rne(float f) {
    unsigned u = __float_as_uint(f);
    u += 0x7FFFu + ((u >> 16) & 1u);
    return (unsigned short)(u >> 16);
}
__device__ __forceinline__ float bf16_to_f32(unsigned short h) {
    return __uint_as_float(((unsigned)h) << 16);
}

// ---------------- W pre-split into MFMA B-fragment layout (single launch) ----
// layout: per (ct, ks) cell of 1024 ushort: [hi: 64 lanes x 8][lo: 64 lanes x 8]
// lane l of a wave holds B[k = ks*32 + (l>>4)*8 + j][col = ct*16 + (l&15)]
__device__ __forceinline__ void prep_one(int idx, int K, int OUT,
    const float* Wq, const float* Wk, const float* Wv, const float* Ws,
    unsigned short* wsp) {
    int NKS  = (K + 31) / 32;
    int j    = idx & 7;
    int lane = (idx >> 3) & 63;
    int cell = idx >> 9;            // ct*NKS + ks
    int ks   = cell % NKS;
    int ct   = cell / NKS;
    int g = lane >> 4, ln = lane & 15;
    int k = ks * 32 + g * 8 + j;
    int c = ct * 16 + ln;
    int mat = c / OUT, cm = c % OUT;
    const float* W = (mat == 0) ? Wq : (mat == 1) ? Wk : (mat == 2) ? Wv : Ws;
    float f = (k < K) ? W[(size_t)k * OUT + cm] : 0.f;
    unsigned short h = f32_to_bf16_rne(f);
    float resid = f - bf16_to_f32(h);
    wsp[(size_t)cell * 1024 + lane * 8 + j]       = h;
    wsp[(size_t)cell * 1024 + 512 + lane * 8 + j] = f32_to_bf16_rne(resid);
}

#define PREP_N0 (16 * 1 * 512)   // 8192
#define PREP_N1 (16 * 2 * 512)   // 16384
#define PREP_N2 (28 * 2 * 512)   // 28672
#define PREP_NT (PREP_N0 + PREP_N1 + PREP_N2)

__global__ __launch_bounds__(256)
void prep_w_all(const float* __restrict__ q0W, const float* __restrict__ k0W,
                const float* __restrict__ v0W, const float* __restrict__ s0W,
                const float* __restrict__ q1W, const float* __restrict__ k1W,
                const float* __restrict__ v1W, const float* __restrict__ s1W,
                const float* __restrict__ q2W, const float* __restrict__ k2W,
                const float* __restrict__ v2W, const float* __restrict__ s2W,
                unsigned short* __restrict__ wsp0,
                unsigned short* __restrict__ wsp1,
                unsigned short* __restrict__ wsp2) {
    int idx = blockIdx.x * 256 + threadIdx.x;
    if (idx < PREP_N0)
        prep_one(idx, 8, 64, q0W, k0W, v0W, s0W, wsp0);
    else if (idx < PREP_N0 + PREP_N1)
        prep_one(idx - PREP_N0, 64, 64, q1W, k1W, v1W, s1W, wsp1);
    else if (idx < PREP_NT)
        prep_one(idx - PREP_N0 - PREP_N1, 64, 112, q2W, k2W, v2W, s2W, wsp2);
}

// ---------------- fused linear via bf16x3 MFMA ----------------
// Y[N x 4*OUT] = X[N x K] @ [Wq|Wk|Wv|Ws] + bias, routed to q (f32), kv (f16
// packed, INTERLEAVED: per 4-channel group [k0..k3 v0..v3]), outskip (f32).
template<int K, int OUT, int CTSPLIT>
__global__ __launch_bounds__(256)
void gemm_qkvs(const float* __restrict__ x,
               const unsigned short* __restrict__ wsp,
               const float* __restrict__ bq, const float* __restrict__ bk,
               const float* __restrict__ bv, const float* __restrict__ bs,
               float* __restrict__ q, unsigned short* __restrict__ kv,
               float* __restrict__ outskip) {
    constexpr int NKS  = (K + 31) / 32;
    constexpr int OUTT = 4 * OUT;
    constexpr int NCT  = OUTT / 16;
    constexpr int CTPB = NCT / CTSPLIT;

    const int t    = threadIdx.x;
    const int lane = t & 63;
    const int wv   = t >> 6;
    const int g    = lane >> 4;
    const int ln   = lane & 15;
    const int rowbase = (blockIdx.x * 4 + wv) * 32;
    if (rowbase >= NN) return;    // no barriers in this kernel

    union F8 { short8v v; unsigned short s[8]; uint4 u4; };

    // ---- load + split A fragments: 2 row-tiles of 16, K along lane>>4 ----
    F8 ahi[2][NKS], alo[2][NKS];
#pragma unroll
    for (int rt = 0; rt < 2; ++rt) {
        int r = rowbase + rt * 16 + ln;
        if (r >= NN) r = NN - 1;                 // stores are guarded
        const float* rowp = x + (size_t)r * K;
#pragma unroll
        for (int ks = 0; ks < NKS; ++ks) {
            const int k0 = ks * 32 + g * 8;
            float xv[8];
            if (k0 + 8 <= K) {
                float4 p0 = *(const float4*)(rowp + k0);
                float4 p1 = *(const float4*)(rowp + k0 + 4);
                xv[0] = p0.x; xv[1] = p0.y; xv[2] = p0.z; xv[3] = p0.w;
                xv[4] = p1.x; xv[5] = p1.y; xv[6] = p1.z; xv[7] = p1.w;
            } else {
#pragma unroll
                for (int j = 0; j < 8; ++j) xv[j] = 0.f;   // K=8 zero-pad
            }
#pragma unroll
            for (int j = 0; j < 8; ++j) {
                unsigned short h = f32_to_bf16_rne(xv[j]);
                ahi[rt][ks].s[j] = h;
                alo[rt][ks].s[j] = f32_to_bf16_rne(xv[j] - bf16_to_f32(h));
            }
        }
    }

    const int ct0 = blockIdx.y * CTPB;
#pragma unroll 1
    for (int ct = ct0; ct < ct0 + CTPB; ++ct) {
        F8 bhi[NKS], blo[NKS];
        const unsigned short* wp = wsp + (size_t)(ct * NKS) * 1024 + lane * 8;
#pragma unroll
        for (int ks = 0; ks < NKS; ++ks) {
            bhi[ks].u4 = *(const uint4*)(wp + ks * 1024);
            blo[ks].u4 = *(const uint4*)(wp + ks * 1024 + 512);
        }

        const int cb  = ct * 16;
        const int mat = cb / OUT;                // wave-uniform
        const int cm  = (cb % OUT) + ln;
        const float* B = (mat == 0) ? bq : (mat == 1) ? bk : (mat == 2) ? bv : bs;
        const float bias = B[cm];
        float4v acc0 = {bias, bias, bias, bias};
        float4v acc1 = {bias, bias, bias, bias};
#pragma unroll
        for (int ks = 0; ks < NKS; ++ks) {
            acc0 = __builtin_amdgcn_mfma_f32_16x16x32_bf16(ahi[0][ks].v, blo[ks].v, acc0, 0, 0, 0);
            acc0 = __builtin_amdgcn_mfma_f32_16x16x32_bf16(alo[0][ks].v, bhi[ks].v, acc0, 0, 0, 0);
            acc0 = __builtin_amdgcn_mfma_f32_16x16x32_bf16(ahi[0][ks].v, bhi[ks].v, acc0, 0, 0, 0);
            acc1 = __builtin_amdgcn_mfma_f32_16x16x32_bf16(ahi[1][ks].v, blo[ks].v, acc1, 0, 0, 0);
            acc1 = __builtin_amdgcn_mfma_f32_16x16x32_bf16(alo[1][ks].v, bhi[ks].v, acc1, 0, 0, 0);
            acc1 = __builtin_amdgcn_mfma_f32_16x16x32_bf16(ahi[1][ks].v, bhi[ks].v, acc1, 0, 0, 0);
        }

        // ---- epilogue: D row = (lane>>4)*4 + reg, col = lane&15 (HW-verified) ----
        if (mat == 0 || mat == 3) {
            float* dst = (mat == 0) ? q : outskip;
#pragma unroll
            for (int rt = 0; rt < 2; ++rt) {
                float4v a = rt ? acc1 : acc0;
#pragma unroll
                for (int reg = 0; reg < 4; ++reg) {
                    int node = rowbase + rt * 16 + g * 4 + reg;
                    if (node < NN)
                        dst[(size_t)node * OUT + cm] = a[reg];
                }
            }
        } else {
            // interleaved kv: channel c -> (c>>2)*8 + (c&3) + (k?0:4)
            const int base = (mat == 1) ? 0 : 4;
            const int kvoff = ((cm >> 2) * 8) + (cm & 3) + base;
#pragma unroll
            for (int rt = 0; rt < 2; ++rt) {
                float4v a = rt ? acc1 : acc0;
#pragma unroll
                for (int reg = 0; reg < 4; ++reg) {
                    int node = rowbase + rt * 16 + g * 4 + reg;
                    float f = a[reg];
                    float other = __shfl_xor(f, 1);  // pair adjacent columns
                    if (node < NN && !(ln & 1)) {
                        unsigned lo16 = __half_as_ushort(__float2half_rn(f));
                        unsigned hi16 = __half_as_ushort(__float2half_rn(other));
                        *(unsigned*)(kv + (size_t)node * (2 * OUT) + kvoff)
                            = lo16 | (hi16 << 16);
                    }
                }
            }
        }
    }
}

// ---------------- deterministic radix partition by dst>>8 (unchanged) ----------------
__global__ __launch_bounds__(256)
void bin_count(const int* __restrict__ ei, int* __restrict__ hist) {
    __shared__ int h[NBUCK];
    const int t = threadIdx.x;
    for (int i = t; i < NBUCK; i += 256) h[i] = 0;
    __syncthreads();
    int e0 = blockIdx.x * EPB;
    int e1 = e0 + EPB < NE ? e0 + EPB : NE;
    for (int i = e0 + t; i < e1; i += 256)
        atomicAdd(&h[ei[NE + i] >> 8], 1);
    __syncthreads();
    for (int i = t; i < NBUCK; i += 256)
        hist[(size_t)i * NBLK + blockIdx.x] = h[i];
}

__global__ __launch_bounds__(SCAN_T)
void gscan1(int* __restrict__ a, int* __restrict__ bsums) {
    __shared__ int lds[SCAN_T];
    int t = threadIdx.x;
    int base = blockIdx.x * SCAN_E + t * 4;
    int vals[4];
    int s = 0;
#pragma unroll
    for (int j = 0; j < 4; ++j) {
        int idx = base + j;
        vals[j] = (idx < HISTN) ? a[idx] : 0;
        s += vals[j];
    }
    lds[t] = s;
    __syncthreads();
    for (int off = 1; off < SCAN_T; off <<= 1) {
        int xx = (t >= off) ? lds[t - off] : 0;
        __syncthreads();
        lds[t] += xx;
        __syncthreads();
    }
    int run = (t > 0) ? lds[t - 1] : 0;
    if (t == SCAN_T - 1) bsums[blockIdx.x] = lds[t];
#pragma unroll
    for (int j = 0; j < 4; ++j) {
        int idx = base + j;
        if (idx < HISTN) a[idx] = run;
        run += vals[j];
    }
}

__global__ __launch_bounds__(256)
void gscan2(int* __restrict__ bsums) {
    __shared__ int lds[256];
    int t = threadIdx.x;
    lds[t] = (t < GS_NB) ? bsums[t] : 0;
    __syncthreads();
    for (int off = 1; off < 256; off <<= 1) {
        int xx = (t >= off) ? lds[t - off] : 0;
        __syncthreads();
        lds[t] += xx;
        __syncthreads();
    }
    if (t < GS_NB) bsums[t] = (t > 0) ? lds[t - 1] : 0;
}

__global__ __launch_bounds__(256)
void gscan3(int* __restrict__ a, const int* __restrict__ bsums,
            int* __restrict__ bstart) {
    int i = blockIdx.x * 256 + threadIdx.x;
    if (i < HISTN) {
        int v = a[i] + bsums[i / SCAN_E];
        a[i] = v;
        if (i % NBLK == 0) bstart[i / NBLK] = v;
    }
    if (i == 0) bstart[NBUCK] = NE;
}

__global__ __launch_bounds__(256)
void bin_scatter(const int* __restrict__ ei, const int* __restrict__ hist,
                 unsigned* __restrict__ ebuf) {
    __shared__ int off[NBUCK];
    const int t = threadIdx.x;
    for (int i = t; i < NBUCK; i += 256)
        off[i] = hist[(size_t)i * NBLK + blockIdx.x];
    __syncthreads();
    int e0 = blockIdx.x * EPB;
    int e1 = e0 + EPB < NE ? e0 + EPB : NE;
    for (int i = e0 + t; i < e1; i += 256) {
        int src = ei[i];
        int dst = ei[NE + i];
        int b = dst >> 8;
        int p = atomicAdd(&off[b], 1);
        ebuf[p] = ((unsigned)(dst & 255) << 17) | (unsigned)src;
    }
}

__global__ __launch_bounds__(256)
void bucket_hist(const int* __restrict__ bstart,
                 const unsigned* __restrict__ ebuf,
                 int* __restrict__ counts) {
    __shared__ int h[256];
    const int b = blockIdx.x;
    const int t = threadIdx.x;
    h[t] = 0;
    __syncthreads();
    int beg = bstart[b], end = bstart[b + 1];
    for (int i = beg + t; i < end; i += 256)
        atomicAdd(&h[ebuf[i] >> 17], 1);
    __syncthreads();
    int d = b * 256 + t;
    if (d < NN) counts[d] = h[t];
}

__global__ __launch_bounds__(SCAN_T)
void scan1(const int* __restrict__ counts, int* __restrict__ offsets,
           int* __restrict__ blocksums) {
    __shared__ int lds[SCAN_T];
    int t = threadIdx.x;
    int base = blockIdx.x * SCAN_E + t * 4;
    int vals[4];
    int s = 0;
#pragma unroll
    for (int j = 0; j < 4; ++j) {
        int idx = base + j;
        vals[j] = (idx < NN) ? counts[idx] : 0;
        s += vals[j];
    }
    lds[t] = s;
    __syncthreads();
    for (int off = 1; off < SCAN_T; off <<= 1) {
        int xx = (t >= off) ? lds[t - off] : 0;
        __syncthreads();
        lds[t] += xx;
        __syncthreads();
    }
    int run = (t > 0) ? lds[t - 1] : 0;
    if (t == SCAN_T - 1) blocksums[blockIdx.x] = lds[t];
#pragma unroll
    for (int j = 0; j < 4; ++j) {
        int idx = base + j;
        if (idx < NN) offsets[idx] = run;
        run += vals[j];
    }
}

__global__ __launch_bounds__(128)
void scan2(int* __restrict__ blocksums) {
    __shared__ int lds[128];
    int t = threadIdx.x;
    lds[t] = (t < SCAN_NB) ? blocksums[t] : 0;
    __syncthreads();
    for (int off = 1; off < 128; off <<= 1) {
        int xx = (t >= off) ? lds[t - off] : 0;
        __syncthreads();
        lds[t] += xx;
        __syncthreads();
    }
    if (t < SCAN_NB) blocksums[t] = (t > 0) ? lds[t - 1] : 0;
}

__global__ __launch_bounds__(256)
void scan3(int* __restrict__ offsets, const int* __restrict__ blocksums) {
    int i = blockIdx.x * blockDim.x + threadIdx.x;
    if (i < NN) offsets[i] = offsets[i] + blocksums[i / SCAN_E];
    if (i == 0) offsets[NN] = NE;
}

__global__ __launch_bounds__(256)
void csr_write(const int* __restrict__ bstart,
               const unsigned* __restrict__ ebuf,
               const int* __restrict__ offsets,
               int* __restrict__ sorted_src) {
    __shared__ int h[256];
    __shared__ int pre[256];
    __shared__ int posi[256];
    __shared__ unsigned srt[BCAP];
    const int b = blockIdx.x;
    const int t = threadIdx.x;
    h[t] = 0;
    __syncthreads();
    int beg = bstart[b];
    int cnt = bstart[b + 1] - beg;
    cnt = cnt < BCAP ? cnt : BCAP;
    const unsigned* buf = ebuf + beg;
    for (int i = t; i < cnt; i += 256)
        atomicAdd(&h[buf[i] >> 17], 1);
    __syncthreads();
    int v = h[t];
    pre[t] = v;
    __syncthreads();
    for (int off = 1; off < 256; off <<= 1) {
        int xx = (t >= off) ? pre[t - off] : 0;
        __syncthreads();
        pre[t] += xx;
        __syncthreads();
    }
    posi[t] = pre[t] - v;
    __syncthreads();
    for (int i = t; i < cnt; i += 256) {
        unsigned u = buf[i];
        int dl = u >> 17;
        int p = atomicAdd(&posi[dl], 1);
        srt[p] = u & 0x1FFFFu;
    }
    __syncthreads();
    const int base = offsets[b << 8];
    for (int i = t; i < cnt; i += 256)
        sorted_src[base + i] = (int)srt[i];
}

// ---- 16-lane row sum via DPP rotates (VALU pipe, no LDS) ----
__device__ __forceinline__ float row16_sum(float x) {
    int y;
    y = __builtin_amdgcn_update_dpp(0, __float_as_int(x), 0x121, 0xF, 0xF, true); x += __int_as_float(y);
    y = __builtin_amdgcn_update_dpp(0, __float_as_int(x), 0x122, 0xF, 0xF, true); x += __int_as_float(y);
    y = __builtin_amdgcn_update_dpp(0, __float_as_int(x), 0x124, 0xF, 0xF, true); x += __int_as_float(y);
    y = __builtin_amdgcn_update_dpp(0, __float_as_int(x), 0x128, 0xF, 0xF, true); x += __int_as_float(y);
    return x;
}

__device__ __forceinline__ float4 h4_to_f4(unsigned wx, unsigned wy) {
    union { unsigned u; __half2 h; } a, b;
    a.u = wx; b.u = wy;
    float2 f0 = __half22float2(a.h);
    float2 f1 = __half22float2(b.h);
    return make_float4(f0.x, f0.y, f1.x, f1.y);
}

// ---------------- fused attention gather: batched online softmax ----------------
// 16-lane groups, 4 edges per batch per group; ONE softmax update per batch
// (4x shorter serial dependency chain than per-edge online softmax).
template<int C, bool RELU>
__global__ __launch_bounds__(256)
void attn_gather(const int* __restrict__ offsets,
                 const int* __restrict__ sorted_src,
                 const float* __restrict__ q,
                 const unsigned short* __restrict__ kv,
                 float* __restrict__ out, float scale) {
    const int wid  = (int)((blockIdx.x * blockDim.x + threadIdx.x) >> 6);
    const int lane = threadIdx.x & 63;
    if (wid >= NN) return;
    const int grp = lane >> 4;
    const int ch  = (lane & 15) * 4;
    constexpr bool P2 = (C > 64);
    const bool hi = P2 && (ch + 64 < C);

    const int beg = offsets[wid], end = offsets[wid + 1];

    const float sl = scale * 1.44269504f;   // fold scale + log2(e) into q
    float4 qv0 = *(const float4*)(q + (size_t)wid * C + ch);
    qv0.x *= sl; qv0.y *= sl; qv0.z *= sl; qv0.w *= sl;
    float4 qv1 = make_float4(0.f, 0.f, 0.f, 0.f);
    if (hi) {
        qv1 = *(const float4*)(q + (size_t)wid * C + ch + 64);
        qv1.x *= sl; qv1.y *= sl; qv1.z *= sl; qv1.w *= sl;
    }

    float m = -FLT_MAX, l = 0.f;
    float4 a0 = make_float4(0.f, 0.f, 0.f, 0.f);
    float4 a1 = make_float4(0.f, 0.f, 0.f, 0.f);

    const unsigned short* kvch = kv + 2 * ch;
    const uint4 zz = make_uint4(0, 0, 0, 0);

    int i = beg + grp;
    while (i < end) {
        // ---- load batch of 4 edges (this group's stride-4 chain) ----
        uint4 t0[4], t1[4];
#pragma unroll
        for (int j = 0; j < 4; ++j) {
            t0[j] = zz; t1[j] = zz;
            int idx = i + 4 * j;
            if (idx < end) {
                const unsigned short* row = kvch + (size_t)sorted_src[idx] * (2 * C);
                t0[j] = *(const uint4*)(row);
                if (hi) t1[j] = *(const uint4*)(row + 128);
            }
        }
        // ---- 4 independent scores (ILP) ----
        float s[4];
#pragma unroll
        for (int j = 0; j < 4; ++j) {
            float4 kf0 = h4_to_f4(t0[j].x, t0[j].y);
            float part = qv0.x * kf0.x + qv0.y * kf0.y + qv0.z * kf0.z + qv0.w * kf0.w;
            if (P2) {
                float4 kf1 = h4_to_f4(t1[j].x, t1[j].y);
                part += qv1.x * kf1.x + qv1.y * kf1.y + qv1.z * kf1.z + qv1.w * kf1.w;
            }
            part = row16_sum(part);                 // log2-domain score
            s[j] = (i + 4 * j < end) ? part : -FLT_MAX;
        }
        // ---- ONE combined softmax update for the batch ----
        float mn = fmaxf(m, fmaxf(fmaxf(s[0], s[1]), fmaxf(s[2], s[3])));
        float al = __builtin_amdgcn_exp2f(m - mn);
        float w[4];
#pragma unroll
        for (int j = 0; j < 4; ++j)
            w[j] = __builtin_amdgcn_exp2f(s[j] - mn);   // -FLT_MAX-mn -> 0
        l = l * al + ((w[0] + w[1]) + (w[2] + w[3]));
        a0.x *= al; a0.y *= al; a0.z *= al; a0.w *= al;
        if (P2) { a1.x *= al; a1.y *= al; a1.z *= al; a1.w *= al; }
#pragma unroll
        for (int j = 0; j < 4; ++j) {
            float4 vf0 = h4_to_f4(t0[j].z, t0[j].w);
            a0.x = fmaf(w[j], vf0.x, a0.x); a0.y = fmaf(w[j], vf0.y, a0.y);
            a0.z = fmaf(w[j], vf0.z, a0.z); a0.w = fmaf(w[j], vf0.w, a0.w);
            if (P2) {
                float4 vf1 = h4_to_f4(t1[j].z, t1[j].w);
                a1.x = fmaf(w[j], vf1.x, a1.x); a1.y = fmaf(w[j], vf1.y, a1.y);
                a1.z = fmaf(w[j], vf1.z, a1.z); a1.w = fmaf(w[j], vf1.w, a1.w);
            }
        }
        m = mn;
        i += 16;
    }

    // merge the 4 groups: butterfly over lane-xor 16, 32
#pragma unroll
    for (int d = 16; d <= 32; d <<= 1) {
        float mo = __shfl_xor(m, d);
        float lo = __shfl_xor(l, d);
        float4 ao0, ao1;
        ao0.x = __shfl_xor(a0.x, d); ao0.y = __shfl_xor(a0.y, d);
        ao0.z = __shfl_xor(a0.z, d); ao0.w = __shfl_xor(a0.w, d);
        if (P2) {
            ao1.x = __shfl_xor(a1.x, d); ao1.y = __shfl_xor(a1.y, d);
            ao1.z = __shfl_xor(a1.z, d); ao1.w = __shfl_xor(a1.w, d);
        }
        float mn = fmaxf(m, mo);
        float e1 = (l  > 0.f) ? __builtin_amdgcn_exp2f(m  - mn) : 0.f;
        float e2 = (lo > 0.f) ? __builtin_amdgcn_exp2f(mo - mn) : 0.f;
        l = l * e1 + lo * e2;
        a0.x = a0.x * e1 + ao0.x * e2; a0.y = a0.y * e1 + ao0.y * e2;
        a0.z = a0.z * e1 + ao0.z * e2; a0.w = a0.w * e1 + ao0.w * e2;
        if (P2) {
            a1.x = a1.x * e1 + ao1.x * e2; a1.y = a1.y * e1 + ao1.y * e2;
            a1.z = a1.z * e1 + ao1.z * e2; a1.w = a1.w * e1 + ao1.w * e2;
        }
        m = mn;
    }

    if (lane < 16) {
        float inv = (l > 0.f) ? 1.f / l : 0.f;
        size_t o = (size_t)wid * C + ch;
        float4 sk = *(const float4*)(out + o);
        float4 r;
        r.x = sk.x + a0.x * inv; r.y = sk.y + a0.y * inv;
        r.z = sk.z + a0.z * inv; r.w = sk.w + a0.w * inv;
        if (RELU) {
            r.x = fmaxf(r.x, 0.f); r.y = fmaxf(r.y, 0.f);
            r.z = fmaxf(r.z, 0.f); r.w = fmaxf(r.w, 0.f);
        }
        *(float4*)(out + o) = r;
        if (hi) {
            float4 sk1 = *(const float4*)(out + o + 64);
            float4 r1;
            r1.x = sk1.x + a1.x * inv; r1.y = sk1.y + a1.y * inv;
            r1.z = sk1.z + a1.z * inv; r1.w = sk1.w + a1.w * inv;
            if (RELU) {
                r1.x = fmaxf(r1.x, 0.f); r1.y = fmaxf(r1.y, 0.f);
                r1.z = fmaxf(r1.z, 0.f); r1.w = fmaxf(r1.w, 0.f);
            }
            *(float4*)(out + o + 64) = r1;
        }
    }
}

// ---------------- host side ----------------
template<int K, int OUT, bool RELU>
static void run_layer(const float* xin, const unsigned short* wsp,
                      const float* const* Wb,
                      const int* offsets, const int* sorted_src,
                      float* q, unsigned short* kv,
                      float* out, hipStream_t stream) {
    constexpr int CTSPLIT = 2;
    dim3 gg((NN + 127) / 128, CTSPLIT);
    gemm_qkvs<K, OUT, CTSPLIT><<<gg, 256, 0, stream>>>(
        xin, wsp, Wb[1], Wb[3], Wb[5], Wb[7], q, kv, out);

    float scale = 1.0f / sqrtf((float)OUT);
    attn_gather<OUT, RELU><<<(NN + 3) / 4, 256, 0, stream>>>(
        offsets, sorted_src, q, kv, out, scale);
}

extern "C" void kernel_launch(void* const* d_in, const int* in_sizes, int n_in,
                              void* d_out, int out_size, void* d_ws, size_t ws_size,
                              hipStream_t stream) {
    const float* x  = (const float*)d_in[0];
    const int*   ei = (const int*)d_in[1];
    const float* Wb0[8], *Wb1[8], *Wb2[8];
    for (int i = 0; i < 8; ++i) {
        Wb0[i] = (const float*)d_in[2 + i];
        Wb1[i] = (const float*)d_in[10 + i];
        Wb2[i] = (const float*)d_in[18 + i];
    }
    float* out = (float*)d_out;

    char* ws = (char*)d_ws;
    const size_t CMAX = 112;
    size_t off = 0;
    float*          q  = (float*)(ws + off);          off += (size_t)NN * CMAX * 4;
    unsigned short* kv = (unsigned short*)(ws + off); off += (size_t)NN * 2 * CMAX * 2;
    float* h0          = (float*)(ws + off);          off += (size_t)NN * 64 * 4;
    float* h1          = (float*)(ws + off);          off += (size_t)NN * 64 * 4;
    int*   sorted_src  = (int*)(ws + off);            off += (size_t)NE * 4;
    int*   counts      = (int*)(ws + off);            off += (size_t)NN * 4;
    int*   offsets     = (int*)(ws + off);            off += (size_t)(NN + 1) * 4;
    int*   blocksums   = (int*)(ws + off);            off += (size_t)SCAN_NB * 4;
    int*   hist        = (int*)(ws + off);            off += (size_t)HISTN * 4;
    int*   gsums       = (int*)(ws + off);            off += (size_t)GS_NB * 4;
    int*   bstart      = (int*)(ws + off);            off += (size_t)(NBUCK + 1) * 4;
    unsigned* ebuf     = (unsigned*)(ws + off);       off += (size_t)NE * 4;
    (void)ws_size; (void)in_sizes; (void)n_in; (void)out_size;

    // ---- build CSR once: deterministic radix partition + per-bucket LDS sort ----
    bin_count<<<NBLK, 256, 0, stream>>>(ei, hist);
    gscan1<<<GS_NB, SCAN_T, 0, stream>>>(hist, gsums);
    gscan2<<<1, 256, 0, stream>>>(gsums);
    gscan3<<<(HISTN + 255) / 256, 256, 0, stream>>>(hist, gsums, bstart);
    bin_scatter<<<NBLK, 256, 0, stream>>>(ei, hist, ebuf);
    bucket_hist<<<NBUCK, 256, 0, stream>>>(bstart, ebuf, counts);
    scan1<<<SCAN_NB, SCAN_T, 0, stream>>>(counts, offsets, blocksums);
    scan2<<<1, 128, 0, stream>>>(blocksums);
    scan3<<<(NN + 255) / 256, 256, 0, stream>>>(offsets, blocksums);
    csr_write<<<NBUCK, 256, 0, stream>>>(bstart, ebuf, offsets, sorted_src);

    // ---- W pre-split (aliased into ebuf; dead after csr_write, stream-ordered) ----
    unsigned short* wspbase =
        (unsigned short*)(((uintptr_t)ebuf + 255) & ~(uintptr_t)255);
    unsigned short* wsp0 = wspbase;                  // 16 ct * 1 ks * 1024
    unsigned short* wsp1 = wsp0 + 16 * 1 * 1024;     // 16 ct * 2 ks * 1024
    unsigned short* wsp2 = wsp1 + 16 * 2 * 1024;     // 28 ct * 2 ks * 1024
    prep_w_all<<<(PREP_NT + 255) / 256, 256, 0, stream>>>(
        Wb0[0], Wb0[2], Wb0[4], Wb0[6],
        Wb1[0], Wb1[2], Wb1[4], Wb1[6],
        Wb2[0], Wb2[2], Wb2[4], Wb2[6],
        wsp0, wsp1, wsp2);

    run_layer<8,  64, true >(x,  wsp0, Wb0, offsets, sorted_src, q, kv, h0,  stream);
    run_layer<64, 64, true >(h0, wsp1, Wb1, offsets, sorted_src, q, kv, h1,  stream);
    run_layer<64, 112, false>(h1, wsp2, Wb2, offsets, sorted_src, q, kv, out, stream);
}

// Round 7
// 540.870 us; speedup vs baseline: 1.0400x; 1.0080x over previous
//
#include <hip/hip_runtime.h>
#include <hip/hip_fp16.h>
#include <math.h>
#include <float.h>
#include <stdint.h>

#define NN 100000
#define NE 1600000

#define SCAN_T 256
#define SCAN_E 1024
#define SCAN_NB ((NN + SCAN_E - 1) / SCAN_E)   // 98

#define NBUCK ((NN + 255) / 256)               // 391 buckets of 256 dsts
#define EPB   4096                              // edges per binning block
#define NBLK  ((NE + EPB - 1) / EPB)            // 391 binning blocks
#define HISTN (NBUCK * NBLK)                    // 152,881
#define GS_NB ((HISTN + SCAN_E - 1) / SCAN_E)   // 150
#define BCAP  5120                              // per-bucket LDS sort capacity

typedef __attribute__((ext_vector_type(8))) short short8v;
typedef __attribute__((ext_vector_type(4))) float float4v;

// ---------------- bf16 split helpers (RNE) ----------------
__device__ __forceinline__ unsigned short f32_to_bf16_rne(float f) {
    unsigned u = __float_as_uint(f);
    u += 0x7FFFu + ((u >> 16) & 1u);
    return (unsigned short)(u >> 16);
}
__device__ __forceinline__ float bf16_to_f32(unsigned short h) {
    return __uint_as_float(((unsigned)h) << 16);
}

// ---------------- W pre-split into MFMA B-fragment layout (single launch) ----
// layout: per (ct, ks) cell of 1024 ushort: [hi: 64 lanes x 8][lo: 64 lanes x 8]
// lane l of a wave holds B[k = ks*32 + (l>>4)*8 + j][col = ct*16 + (l&15)]
__device__ __forceinline__ void prep_one(int idx, int K, int OUT,
    const float* Wq, const float* Wk, const float* Wv, const float* Ws,
    unsigned short* wsp) {
    int NKS  = (K + 31) / 32;
    int j    = idx & 7;
    int lane = (idx >> 3) & 63;
    int cell = idx >> 9;            // ct*NKS + ks
    int ks   = cell % NKS;
    int ct   = cell / NKS;
    int g = lane >> 4, ln = lane & 15;
    int k = ks * 32 + g * 8 + j;
    int c = ct * 16 + ln;
    int mat = c / OUT, cm = c % OUT;
    const float* W = (mat == 0) ? Wq : (mat == 1) ? Wk : (mat == 2) ? Wv : Ws;
    float f = (k < K) ? W[(size_t)k * OUT + cm] : 0.f;
    unsigned short h = f32_to_bf16_rne(f);
    float resid = f - bf16_to_f32(h);
    wsp[(size_t)cell * 1024 + lane * 8 + j]       = h;
    wsp[(size_t)cell * 1024 + 512 + lane * 8 + j] = f32_to_bf16_rne(resid);
}

#define PREP_N0 (16 * 1 * 512)   // 8192
#define PREP_N1 (16 * 2 * 512)   // 16384
#define PREP_N2 (28 * 2 * 512)   // 28672
#define PREP_NT (PREP_N0 + PREP_N1 + PREP_N2)

__global__ __launch_bounds__(256)
void prep_w_all(const float* __restrict__ q0W, const float* __restrict__ k0W,
                const float* __restrict__ v0W, const float* __restrict__ s0W,
                const float* __restrict__ q1W, const float* __restrict__ k1W,
                const float* __restrict__ v1W, const float* __restrict__ s1W,
                const float* __restrict__ q2W, const float* __restrict__ k2W,
                const float* __restrict__ v2W, const float* __restrict__ s2W,
                unsigned short* __restrict__ wsp0,
                unsigned short* __restrict__ wsp1,
                unsigned short* __restrict__ wsp2) {
    int idx = blockIdx.x * 256 + threadIdx.x;
    if (idx < PREP_N0)
        prep_one(idx, 8, 64, q0W, k0W, v0W, s0W, wsp0);
    else if (idx < PREP_N0 + PREP_N1)
        prep_one(idx - PREP_N0, 64, 64, q1W, k1W, v1W, s1W, wsp1);
    else if (idx < PREP_NT)
        prep_one(idx - PREP_N0 - PREP_N1, 64, 112, q2W, k2W, v2W, s2W, wsp2);
}

// ---------------- fused linear via bf16x3 MFMA ----------------
// Y[N x 4*OUT] = X[N x K] @ [Wq|Wk|Wv|Ws] + bias, routed to q (f32), kv (f16
// packed, INTERLEAVED: per 4-channel group [k0..k3 v0..v3]), outskip (f32).
template<int K, int OUT, int CTSPLIT>
__global__ __launch_bounds__(256)
void gemm_qkvs(const float* __restrict__ x,
               const unsigned short* __restrict__ wsp,
               const float* __restrict__ bq, const float* __restrict__ bk,
               const float* __restrict__ bv, const float* __restrict__ bs,
               float* __restrict__ q, unsigned short* __restrict__ kv,
               float* __restrict__ outskip) {
    constexpr int NKS  = (K + 31) / 32;
    constexpr int OUTT = 4 * OUT;
    constexpr int NCT  = OUTT / 16;
    constexpr int CTPB = NCT / CTSPLIT;

    const int t    = threadIdx.x;
    const int lane = t & 63;
    const int wv   = t >> 6;
    const int g    = lane >> 4;
    const int ln   = lane & 15;
    const int rowbase = (blockIdx.x * 4 + wv) * 32;
    if (rowbase >= NN) return;    // no barriers in this kernel

    union F8 { short8v v; unsigned short s[8]; uint4 u4; };

    // ---- load + split A fragments: 2 row-tiles of 16, K along lane>>4 ----
    F8 ahi[2][NKS], alo[2][NKS];
#pragma unroll
    for (int rt = 0; rt < 2; ++rt) {
        int r = rowbase + rt * 16 + ln;
        if (r >= NN) r = NN - 1;                 // stores are guarded
        const float* rowp = x + (size_t)r * K;
#pragma unroll
        for (int ks = 0; ks < NKS; ++ks) {
            const int k0 = ks * 32 + g * 8;
            float xv[8];
            if (k0 + 8 <= K) {
                float4 p0 = *(const float4*)(rowp + k0);
                float4 p1 = *(const float4*)(rowp + k0 + 4);
                xv[0] = p0.x; xv[1] = p0.y; xv[2] = p0.z; xv[3] = p0.w;
                xv[4] = p1.x; xv[5] = p1.y; xv[6] = p1.z; xv[7] = p1.w;
            } else {
#pragma unroll
                for (int j = 0; j < 8; ++j) xv[j] = 0.f;   // K=8 zero-pad
            }
#pragma unroll
            for (int j = 0; j < 8; ++j) {
                unsigned short h = f32_to_bf16_rne(xv[j]);
                ahi[rt][ks].s[j] = h;
                alo[rt][ks].s[j] = f32_to_bf16_rne(xv[j] - bf16_to_f32(h));
            }
        }
    }

    const int ct0 = blockIdx.y * CTPB;
#pragma unroll 1
    for (int ct = ct0; ct < ct0 + CTPB; ++ct) {
        F8 bhi[NKS], blo[NKS];
        const unsigned short* wp = wsp + (size_t)(ct * NKS) * 1024 + lane * 8;
#pragma unroll
        for (int ks = 0; ks < NKS; ++ks) {
            bhi[ks].u4 = *(const uint4*)(wp + ks * 1024);
            blo[ks].u4 = *(const uint4*)(wp + ks * 1024 + 512);
        }

        const int cb  = ct * 16;
        const int mat = cb / OUT;                // wave-uniform
        const int cm  = (cb % OUT) + ln;
        const float* B = (mat == 0) ? bq : (mat == 1) ? bk : (mat == 2) ? bv : bs;
        const float bias = B[cm];
        float4v acc0 = {bias, bias, bias, bias};
        float4v acc1 = {bias, bias, bias, bias};
#pragma unroll
        for (int ks = 0; ks < NKS; ++ks) {
            acc0 = __builtin_amdgcn_mfma_f32_16x16x32_bf16(ahi[0][ks].v, blo[ks].v, acc0, 0, 0, 0);
            acc0 = __builtin_amdgcn_mfma_f32_16x16x32_bf16(alo[0][ks].v, bhi[ks].v, acc0, 0, 0, 0);
            acc0 = __builtin_amdgcn_mfma_f32_16x16x32_bf16(ahi[0][ks].v, bhi[ks].v, acc0, 0, 0, 0);
            acc1 = __builtin_amdgcn_mfma_f32_16x16x32_bf16(ahi[1][ks].v, blo[ks].v, acc1, 0, 0, 0);
            acc1 = __builtin_amdgcn_mfma_f32_16x16x32_bf16(alo[1][ks].v, bhi[ks].v, acc1, 0, 0, 0);
            acc1 = __builtin_amdgcn_mfma_f32_16x16x32_bf16(ahi[1][ks].v, bhi[ks].v, acc1, 0, 0, 0);
        }

        // ---- epilogue: D row = (lane>>4)*4 + reg, col = lane&15 (HW-verified) ----
        if (mat == 0 || mat == 3) {
            float* dst = (mat == 0) ? q : outskip;
#pragma unroll
            for (int rt = 0; rt < 2; ++rt) {
                float4v a = rt ? acc1 : acc0;
#pragma unroll
                for (int reg = 0; reg < 4; ++reg) {
                    int node = rowbase + rt * 16 + g * 4 + reg;
                    if (node < NN)
                        dst[(size_t)node * OUT + cm] = a[reg];
                }
            }
        } else {
            // interleaved kv: channel c -> (c>>2)*8 + (c&3) + (k?0:4)
            const int base = (mat == 1) ? 0 : 4;
            const int kvoff = ((cm >> 2) * 8) + (cm & 3) + base;
#pragma unroll
            for (int rt = 0; rt < 2; ++rt) {
                float4v a = rt ? acc1 : acc0;
#pragma unroll
                for (int reg = 0; reg < 4; ++reg) {
                    int node = rowbase + rt * 16 + g * 4 + reg;
                    float f = a[reg];
                    float other = __shfl_xor(f, 1);  // pair adjacent columns
                    if (node < NN && !(ln & 1)) {
                        unsigned lo16 = __half_as_ushort(__float2half_rn(f));
                        unsigned hi16 = __half_as_ushort(__float2half_rn(other));
                        *(unsigned*)(kv + (size_t)node * (2 * OUT) + kvoff)
                            = lo16 | (hi16 << 16);
                    }
                }
            }
        }
    }
}

// ---------------- deterministic radix partition by dst>>8 (unchanged) ----------------
__global__ __launch_bounds__(256)
void bin_count(const int* __restrict__ ei, int* __restrict__ hist) {
    __shared__ int h[NBUCK];
    const int t = threadIdx.x;
    for (int i = t; i < NBUCK; i += 256) h[i] = 0;
    __syncthreads();
    int e0 = blockIdx.x * EPB;
    int e1 = e0 + EPB < NE ? e0 + EPB : NE;
    for (int i = e0 + t; i < e1; i += 256)
        atomicAdd(&h[ei[NE + i] >> 8], 1);
    __syncthreads();
    for (int i = t; i < NBUCK; i += 256)
        hist[(size_t)i * NBLK + blockIdx.x] = h[i];
}

__global__ __launch_bounds__(SCAN_T)
void gscan1(int* __restrict__ a, int* __restrict__ bsums) {
    __shared__ int lds[SCAN_T];
    int t = threadIdx.x;
    int base = blockIdx.x * SCAN_E + t * 4;
    int vals[4];
    int s = 0;
#pragma unroll
    for (int j = 0; j < 4; ++j) {
        int idx = base + j;
        vals[j] = (idx < HISTN) ? a[idx] : 0;
        s += vals[j];
    }
    lds[t] = s;
    __syncthreads();
    for (int off = 1; off < SCAN_T; off <<= 1) {
        int xx = (t >= off) ? lds[t - off] : 0;
        __syncthreads();
        lds[t] += xx;
        __syncthreads();
    }
    int run = (t > 0) ? lds[t - 1] : 0;
    if (t == SCAN_T - 1) bsums[blockIdx.x] = lds[t];
#pragma unroll
    for (int j = 0; j < 4; ++j) {
        int idx = base + j;
        if (idx < HISTN) a[idx] = run;
        run += vals[j];
    }
}

__global__ __launch_bounds__(256)
void gscan2(int* __restrict__ bsums) {
    __shared__ int lds[256];
    int t = threadIdx.x;
    lds[t] = (t < GS_NB) ? bsums[t] : 0;
    __syncthreads();
    for (int off = 1; off < 256; off <<= 1) {
        int xx = (t >= off) ? lds[t - off] : 0;
        __syncthreads();
        lds[t] += xx;
        __syncthreads();
    }
    if (t < GS_NB) bsums[t] = (t > 0) ? lds[t - 1] : 0;
}

__global__ __launch_bounds__(256)
void gscan3(int* __restrict__ a, const int* __restrict__ bsums,
            int* __restrict__ bstart) {
    int i = blockIdx.x * 256 + threadIdx.x;
    if (i < HISTN) {
        int v = a[i] + bsums[i / SCAN_E];
        a[i] = v;
        if (i % NBLK == 0) bstart[i / NBLK] = v;
    }
    if (i == 0) bstart[NBUCK] = NE;
}

__global__ __launch_bounds__(256)
void bin_scatter(const int* __restrict__ ei, const int* __restrict__ hist,
                 unsigned* __restrict__ ebuf) {
    __shared__ int off[NBUCK];
    const int t = threadIdx.x;
    for (int i = t; i < NBUCK; i += 256)
        off[i] = hist[(size_t)i * NBLK + blockIdx.x];
    __syncthreads();
    int e0 = blockIdx.x * EPB;
    int e1 = e0 + EPB < NE ? e0 + EPB : NE;
    for (int i = e0 + t; i < e1; i += 256) {
        int src = ei[i];
        int dst = ei[NE + i];
        int b = dst >> 8;
        int p = atomicAdd(&off[b], 1);
        ebuf[p] = ((unsigned)(dst & 255) << 17) | (unsigned)src;
    }
}

__global__ __launch_bounds__(256)
void bucket_hist(const int* __restrict__ bstart,
                 const unsigned* __restrict__ ebuf,
                 int* __restrict__ counts) {
    __shared__ int h[256];
    const int b = blockIdx.x;
    const int t = threadIdx.x;
    h[t] = 0;
    __syncthreads();
    int beg = bstart[b], end = bstart[b + 1];
    for (int i = beg + t; i < end; i += 256)
        atomicAdd(&h[ebuf[i] >> 17], 1);
    __syncthreads();
    int d = b * 256 + t;
    if (d < NN) counts[d] = h[t];
}

__global__ __launch_bounds__(SCAN_T)
void scan1(const int* __restrict__ counts, int* __restrict__ offsets,
           int* __restrict__ blocksums) {
    __shared__ int lds[SCAN_T];
    int t = threadIdx.x;
    int base = blockIdx.x * SCAN_E + t * 4;
    int vals[4];
    int s = 0;
#pragma unroll
    for (int j = 0; j < 4; ++j) {
        int idx = base + j;
        vals[j] = (idx < NN) ? counts[idx] : 0;
        s += vals[j];
    }
    lds[t] = s;
    __syncthreads();
    for (int off = 1; off < SCAN_T; off <<= 1) {
        int xx = (t >= off) ? lds[t - off] : 0;
        __syncthreads();
        lds[t] += xx;
        __syncthreads();
    }
    int run = (t > 0) ? lds[t - 1] : 0;
    if (t == SCAN_T - 1) blocksums[blockIdx.x] = lds[t];
#pragma unroll
    for (int j = 0; j < 4; ++j) {
        int idx = base + j;
        if (idx < NN) offsets[idx] = run;
        run += vals[j];
    }
}

__global__ __launch_bounds__(128)
void scan2(int* __restrict__ blocksums) {
    __shared__ int lds[128];
    int t = threadIdx.x;
    lds[t] = (t < SCAN_NB) ? blocksums[t] : 0;
    __syncthreads();
    for (int off = 1; off < 128; off <<= 1) {
        int xx = (t >= off) ? lds[t - off] : 0;
        __syncthreads();
        lds[t] += xx;
        __syncthreads();
    }
    if (t < SCAN_NB) blocksums[t] = (t > 0) ? lds[t - 1] : 0;
}

__global__ __launch_bounds__(256)
void scan3(int* __restrict__ offsets, const int* __restrict__ blocksums) {
    int i = blockIdx.x * blockDim.x + threadIdx.x;
    if (i < NN) offsets[i] = offsets[i] + blocksums[i / SCAN_E];
    if (i == 0) offsets[NN] = NE;
}

__global__ __launch_bounds__(256)
void csr_write(const int* __restrict__ bstart,
               const unsigned* __restrict__ ebuf,
               const int* __restrict__ offsets,
               int* __restrict__ sorted_src) {
    __shared__ int h[256];
    __shared__ int pre[256];
    __shared__ int posi[256];
    __shared__ unsigned srt[BCAP];
    const int b = blockIdx.x;
    const int t = threadIdx.x;
    h[t] = 0;
    __syncthreads();
    int beg = bstart[b];
    int cnt = bstart[b + 1] - beg;
    cnt = cnt < BCAP ? cnt : BCAP;
    const unsigned* buf = ebuf + beg;
    for (int i = t; i < cnt; i += 256)
        atomicAdd(&h[buf[i] >> 17], 1);
    __syncthreads();
    int v = h[t];
    pre[t] = v;
    __syncthreads();
    for (int off = 1; off < 256; off <<= 1) {
        int xx = (t >= off) ? pre[t - off] : 0;
        __syncthreads();
        pre[t] += xx;
        __syncthreads();
    }
    posi[t] = pre[t] - v;
    __syncthreads();
    for (int i = t; i < cnt; i += 256) {
        unsigned u = buf[i];
        int dl = u >> 17;
        int p = atomicAdd(&posi[dl], 1);
        srt[p] = u & 0x1FFFFu;
    }
    __syncthreads();
    const int base = offsets[b << 8];
    for (int i = t; i < cnt; i += 256)
        sorted_src[base + i] = (int)srt[i];
}

// ---- 16-lane row sum via DPP rotates (VALU pipe, no LDS) ----
__device__ __forceinline__ float row16_sum(float x) {
    int y;
    y = __builtin_amdgcn_update_dpp(0, __float_as_int(x), 0x121, 0xF, 0xF, true); x += __int_as_float(y);
    y = __builtin_amdgcn_update_dpp(0, __float_as_int(x), 0x122, 0xF, 0xF, true); x += __int_as_float(y);
    y = __builtin_amdgcn_update_dpp(0, __float_as_int(x), 0x124, 0xF, 0xF, true); x += __int_as_float(y);
    y = __builtin_amdgcn_update_dpp(0, __float_as_int(x), 0x128, 0xF, 0xF, true); x += __int_as_float(y);
    return x;
}

// dot-accumulate with f16 source: mix-fma friendly (exact f16->f32 in-op)
__device__ __forceinline__ float mix2(float acc, unsigned u, float q0, float q1) {
    __half2 h = *(__half2*)&u;
    acc = fmaf(__half2float(h.x), q0, acc);
    return fmaf(__half2float(h.y), q1, acc);
}
// a += w * v for a packed f16 pair (mix-fma friendly)
__device__ __forceinline__ void vmix2(float& a0, float& a1, unsigned u, float w) {
    __half2 h = *(__half2*)&u;
    a0 = fmaf(__half2float(h.x), w, a0);
    a1 = fmaf(__half2float(h.y), w, a1);
}

// ---------------- fused attention gather: batched online softmax ----------------
// block = 128 (2 dsts) to minimize degree-tail wave-slot holding.
// 16-lane groups, 4 edges per batch per group; ONE softmax update per batch.
template<int C, bool RELU>
__global__ __launch_bounds__(128)
void attn_gather(const int* __restrict__ offsets,
                 const int* __restrict__ sorted_src,
                 const float* __restrict__ q,
                 const unsigned short* __restrict__ kv,
                 float* __restrict__ out, float scale) {
    const int wid  = (int)((blockIdx.x * blockDim.x + threadIdx.x) >> 6);
    const int lane = threadIdx.x & 63;
    if (wid >= NN) return;
    const int grp = lane >> 4;
    const int ch  = (lane & 15) * 4;
    constexpr bool P2 = (C > 64);
    const bool hi = P2 && (ch + 64 < C);

    const int beg = offsets[wid], end = offsets[wid + 1];

    const float sl = scale * 1.44269504f;   // fold scale + log2(e) into q
    float4 qv0 = *(const float4*)(q + (size_t)wid * C + ch);
    qv0.x *= sl; qv0.y *= sl; qv0.z *= sl; qv0.w *= sl;
    float4 qv1 = make_float4(0.f, 0.f, 0.f, 0.f);
    if (hi) {
        qv1 = *(const float4*)(q + (size_t)wid * C + ch + 64);
        qv1.x *= sl; qv1.y *= sl; qv1.z *= sl; qv1.w *= sl;
    }

    float m = -FLT_MAX, l = 0.f;
    float4 a0 = make_float4(0.f, 0.f, 0.f, 0.f);
    float4 a1 = make_float4(0.f, 0.f, 0.f, 0.f);

    const unsigned short* kvch = kv + 2 * ch;
    const uint4 zz = make_uint4(0, 0, 0, 0);

    int i = beg + grp;
    while (i < end) {
        // ---- load batch of 4 edges (this group's stride-4 chain) ----
        uint4 t0[4], t1[4];
#pragma unroll
        for (int j = 0; j < 4; ++j) {
            t0[j] = zz; t1[j] = zz;
            int idx = i + 4 * j;
            if (idx < end) {
                const unsigned short* row = kvch + (size_t)sorted_src[idx] * (2 * C);
                t0[j] = *(const uint4*)(row);
                if (hi) t1[j] = *(const uint4*)(row + 128);
            }
        }
        // ---- 4 independent scores (ILP, mix-fma) ----
        float s[4];
#pragma unroll
        for (int j = 0; j < 4; ++j) {
            float part = 0.f;
            part = mix2(part, t0[j].x, qv0.x, qv0.y);
            part = mix2(part, t0[j].y, qv0.z, qv0.w);
            if (P2) {
                part = mix2(part, t1[j].x, qv1.x, qv1.y);
                part = mix2(part, t1[j].y, qv1.z, qv1.w);
            }
            part = row16_sum(part);                 // log2-domain score
            s[j] = (i + 4 * j < end) ? part : -FLT_MAX;
        }
        // ---- ONE combined softmax update for the batch ----
        float mn = fmaxf(m, fmaxf(fmaxf(s[0], s[1]), fmaxf(s[2], s[3])));
        float al = __builtin_amdgcn_exp2f(m - mn);
        float w[4];
#pragma unroll
        for (int j = 0; j < 4; ++j)
            w[j] = __builtin_amdgcn_exp2f(s[j] - mn);   // -FLT_MAX-mn -> 0
        l = l * al + ((w[0] + w[1]) + (w[2] + w[3]));
        a0.x *= al; a0.y *= al; a0.z *= al; a0.w *= al;
        if (P2) { a1.x *= al; a1.y *= al; a1.z *= al; a1.w *= al; }
#pragma unroll
        for (int j = 0; j < 4; ++j) {
            vmix2(a0.x, a0.y, t0[j].z, w[j]);
            vmix2(a0.z, a0.w, t0[j].w, w[j]);
            if (P2) {
                vmix2(a1.x, a1.y, t1[j].z, w[j]);
                vmix2(a1.z, a1.w, t1[j].w, w[j]);
            }
        }
        m = mn;
        i += 16;
    }

    // merge the 4 groups: butterfly over lane-xor 16, 32
#pragma unroll
    for (int d = 16; d <= 32; d <<= 1) {
        float mo = __shfl_xor(m, d);
        float lo = __shfl_xor(l, d);
        float4 ao0, ao1;
        ao0.x = __shfl_xor(a0.x, d); ao0.y = __shfl_xor(a0.y, d);
        ao0.z = __shfl_xor(a0.z, d); ao0.w = __shfl_xor(a0.w, d);
        if (P2) {
            ao1.x = __shfl_xor(a1.x, d); ao1.y = __shfl_xor(a1.y, d);
            ao1.z = __shfl_xor(a1.z, d); ao1.w = __shfl_xor(a1.w, d);
        }
        float mn = fmaxf(m, mo);
        float e1 = (l  > 0.f) ? __builtin_amdgcn_exp2f(m  - mn) : 0.f;
        float e2 = (lo > 0.f) ? __builtin_amdgcn_exp2f(mo - mn) : 0.f;
        l = l * e1 + lo * e2;
        a0.x = a0.x * e1 + ao0.x * e2; a0.y = a0.y * e1 + ao0.y * e2;
        a0.z = a0.z * e1 + ao0.z * e2; a0.w = a0.w * e1 + ao0.w * e2;
        if (P2) {
            a1.x = a1.x * e1 + ao1.x * e2; a1.y = a1.y * e1 + ao1.y * e2;
            a1.z = a1.z * e1 + ao1.z * e2; a1.w = a1.w * e1 + ao1.w * e2;
        }
        m = mn;
    }

    if (lane < 16) {
        float inv = (l > 0.f) ? 1.f / l : 0.f;
        size_t o = (size_t)wid * C + ch;
        float4 sk = *(const float4*)(out + o);
        float4 r;
        r.x = sk.x + a0.x * inv; r.y = sk.y + a0.y * inv;
        r.z = sk.z + a0.z * inv; r.w = sk.w + a0.w * inv;
        if (RELU) {
            r.x = fmaxf(r.x, 0.f); r.y = fmaxf(r.y, 0.f);
            r.z = fmaxf(r.z, 0.f); r.w = fmaxf(r.w, 0.f);
        }
        *(float4*)(out + o) = r;
        if (hi) {
            float4 sk1 = *(const float4*)(out + o + 64);
            float4 r1;
            r1.x = sk1.x + a1.x * inv; r1.y = sk1.y + a1.y * inv;
            r1.z = sk1.z + a1.z * inv; r1.w = sk1.w + a1.w * inv;
            if (RELU) {
                r1.x = fmaxf(r1.x, 0.f); r1.y = fmaxf(r1.y, 0.f);
                r1.z = fmaxf(r1.z, 0.f); r1.w = fmaxf(r1.w, 0.f);
            }
            *(float4*)(out + o + 64) = r1;
        }
    }
}

// ---------------- host side ----------------
template<int K, int OUT, bool RELU>
static void run_layer(const float* xin, const unsigned short* wsp,
                      const float* const* Wb,
                      const int* offsets, const int* sorted_src,
                      float* q, unsigned short* kv,
                      float* out, hipStream_t stream) {
    constexpr int CTSPLIT = 2;
    dim3 gg((NN + 127) / 128, CTSPLIT);
    gemm_qkvs<K, OUT, CTSPLIT><<<gg, 256, 0, stream>>>(
        xin, wsp, Wb[1], Wb[3], Wb[5], Wb[7], q, kv, out);

    float scale = 1.0f / sqrtf((float)OUT);
    attn_gather<OUT, RELU><<<(NN + 1) / 2, 128, 0, stream>>>(
        offsets, sorted_src, q, kv, out, scale);
}

extern "C" void kernel_launch(void* const* d_in, const int* in_sizes, int n_in,
                              void* d_out, int out_size, void* d_ws, size_t ws_size,
                              hipStream_t stream) {
    const float* x  = (const float*)d_in[0];
    const int*   ei = (const int*)d_in[1];
    const float* Wb0[8], *Wb1[8], *Wb2[8];
    for (int i = 0; i < 8; ++i) {
        Wb0[i] = (const float*)d_in[2 + i];
        Wb1[i] = (const float*)d_in[10 + i];
        Wb2[i] = (const float*)d_in[18 + i];
    }
    float* out = (float*)d_out;

    char* ws = (char*)d_ws;
    const size_t CMAX = 112;
    size_t off = 0;
    float*          q  = (float*)(ws + off);          off += (size_t)NN * CMAX * 4;
    unsigned short* kv = (unsigned short*)(ws + off); off += (size_t)NN * 2 * CMAX * 2;
    float* h0          = (float*)(ws + off);          off += (size_t)NN * 64 * 4;
    float* h1          = (float*)(ws + off);          off += (size_t)NN * 64 * 4;
    int*   sorted_src  = (int*)(ws + off);            off += (size_t)NE * 4;
    int*   counts      = (int*)(ws + off);            off += (size_t)NN * 4;
    int*   offsets     = (int*)(ws + off);            off += (size_t)(NN + 1) * 4;
    int*   blocksums   = (int*)(ws + off);            off += (size_t)SCAN_NB * 4;
    int*   hist        = (int*)(ws + off);            off += (size_t)HISTN * 4;
    int*   gsums       = (int*)(ws + off);            off += (size_t)GS_NB * 4;
    int*   bstart      = (int*)(ws + off);            off += (size_t)(NBUCK + 1) * 4;
    unsigned* ebuf     = (unsigned*)(ws + off);       off += (size_t)NE * 4;
    (void)ws_size; (void)in_sizes; (void)n_in; (void)out_size;

    // ---- build CSR once: deterministic radix partition + per-bucket LDS sort ----
    bin_count<<<NBLK, 256, 0, stream>>>(ei, hist);
    gscan1<<<GS_NB, SCAN_T, 0, stream>>>(hist, gsums);
    gscan2<<<1, 256, 0, stream>>>(gsums);
    gscan3<<<(HISTN + 255) / 256, 256, 0, stream>>>(hist, gsums, bstart);
    bin_scatter<<<NBLK, 256, 0, stream>>>(ei, hist, ebuf);
    bucket_hist<<<NBUCK, 256, 0, stream>>>(bstart, ebuf, counts);
    scan1<<<SCAN_NB, SCAN_T, 0, stream>>>(counts, offsets, blocksums);
    scan2<<<1, 128, 0, stream>>>(blocksums);
    scan3<<<(NN + 255) / 256, 256, 0, stream>>>(offsets, blocksums);
    csr_write<<<NBUCK, 256, 0, stream>>>(bstart, ebuf, offsets, sorted_src);

    // ---- W pre-split (aliased into ebuf; dead after csr_write, stream-ordered) ----
    unsigned short* wspbase =
        (unsigned short*)(((uintptr_t)ebuf + 255) & ~(uintptr_t)255);
    unsigned short* wsp0 = wspbase;                  // 16 ct * 1 ks * 1024
    unsigned short* wsp1 = wsp0 + 16 * 1 * 1024;     // 16 ct * 2 ks * 1024
    unsigned short* wsp2 = wsp1 + 16 * 2 * 1024;     // 28 ct * 2 ks * 1024
    prep_w_all<<<(PREP_NT + 255) / 256, 256, 0, stream>>>(
        Wb0[0], Wb0[2], Wb0[4], Wb0[6],
        Wb1[0], Wb1[2], Wb1[4], Wb1[6],
        Wb2[0], Wb2[2], Wb2[4], Wb2[6],
        wsp0, wsp1, wsp2);

    run_layer<8,  64, true >(x,  wsp0, Wb0, offsets, sorted_src, q, kv, h0,  stream);
    run_layer<64, 64, true >(h0, wsp1, Wb1, offsets, sorted_src, q, kv, h1,  stream);
    run_layer<64, 112, false>(h1, wsp2, Wb2, offsets, sorted_src, q, kv, out, stream);
}

// Round 8
// 524.433 us; speedup vs baseline: 1.0726x; 1.0313x over previous
//
#include <hip/hip_runtime.h>
#include <hip/hip_fp16.h>
#include <math.h>
#include <float.h>
#include <stdint.h>

#define NN 100000
#define NE 1600000

#define SCAN_T 256
#define SCAN_E 1024

#define NBUCK ((NN + 255) / 256)               // 391 buckets of 256 dsts
#define EPB   4096                              // edges per binning block
#define NBLK  ((NE + EPB - 1) / EPB)            // 391 binning blocks
#define HISTN (NBUCK * NBLK)                    // 152,881
#define GS_NB ((HISTN + SCAN_E - 1) / SCAN_E)   // 150
#define BCAP  5120                              // per-bucket LDS sort capacity

typedef __attribute__((ext_vector_type(8))) short short8v;
typedef __attribute__((ext_vector_type(4))) float float4v;

// ---------------- bf16 split helpers (RNE) ----------------
__device__ __forceinline__ unsigned short f32_to_bf16_rne(float f) {
    unsigned u = __float_as_uint(f);
    u += 0x7FFFu + ((u >> 16) & 1u);
    return (unsigned short)(u >> 16);
}
__device__ __forceinline__ float bf16_to_f32(unsigned short h) {
    return __uint_as_float(((unsigned)h) << 16);
}

// ---------------- W pre-split into MFMA B-fragment layout (single launch) ----
// layout: per (ct, ks) cell of 1024 ushort: [hi: 64 lanes x 8][lo: 64 lanes x 8]
// lane l of a wave holds B[k = ks*32 + (l>>4)*8 + j][col = ct*16 + (l&15)]
__device__ __forceinline__ void prep_one(int idx, int K, int OUT,
    const float* Wq, const float* Wk, const float* Wv, const float* Ws,
    unsigned short* wsp) {
    int NKS  = (K + 31) / 32;
    int j    = idx & 7;
    int lane = (idx >> 3) & 63;
    int cell = idx >> 9;            // ct*NKS + ks
    int ks   = cell % NKS;
    int ct   = cell / NKS;
    int g = lane >> 4, ln = lane & 15;
    int k = ks * 32 + g * 8 + j;
    int c = ct * 16 + ln;
    int mat = c / OUT, cm = c % OUT;
    const float* W = (mat == 0) ? Wq : (mat == 1) ? Wk : (mat == 2) ? Wv : Ws;
    float f = (k < K) ? W[(size_t)k * OUT + cm] : 0.f;
    unsigned short h = f32_to_bf16_rne(f);
    float resid = f - bf16_to_f32(h);
    wsp[(size_t)cell * 1024 + lane * 8 + j]       = h;
    wsp[(size_t)cell * 1024 + 512 + lane * 8 + j] = f32_to_bf16_rne(resid);
}

#define PREP_N0 (16 * 1 * 512)   // 8192
#define PREP_N1 (16 * 2 * 512)   // 16384
#define PREP_N2 (28 * 2 * 512)   // 28672
#define PREP_NT (PREP_N0 + PREP_N1 + PREP_N2)

__global__ __launch_bounds__(256)
void prep_w_all(const float* __restrict__ q0W, const float* __restrict__ k0W,
                const float* __restrict__ v0W, const float* __restrict__ s0W,
                const float* __restrict__ q1W, const float* __restrict__ k1W,
                const float* __restrict__ v1W, const float* __restrict__ s1W,
                const float* __restrict__ q2W, const float* __restrict__ k2W,
                const float* __restrict__ v2W, const float* __restrict__ s2W,
                unsigned short* __restrict__ wsp0,
                unsigned short* __restrict__ wsp1,
                unsigned short* __restrict__ wsp2) {
    int idx = blockIdx.x * 256 + threadIdx.x;
    if (idx < PREP_N0)
        prep_one(idx, 8, 64, q0W, k0W, v0W, s0W, wsp0);
    else if (idx < PREP_N0 + PREP_N1)
        prep_one(idx - PREP_N0, 64, 64, q1W, k1W, v1W, s1W, wsp1);
    else if (idx < PREP_NT)
        prep_one(idx - PREP_N0 - PREP_N1, 64, 112, q2W, k2W, v2W, s2W, wsp2);
}

// ---------------- fused linear via bf16x3 MFMA ----------------
// Y[N x 4*OUT] = X[N x K] @ [Wq|Wk|Wv|Ws] + bias, routed to q (f32), kv (f16
// packed, INTERLEAVED: per 4-channel group [k0..k3 v0..v3]), outskip (f32).
// CTSPLIT=1: A fragments loaded once per block, all column tiles computed.
template<int K, int OUT>
__global__ __launch_bounds__(256)
void gemm_qkvs(const float* __restrict__ x,
               const unsigned short* __restrict__ wsp,
               const float* __restrict__ bq, const float* __restrict__ bk,
               const float* __restrict__ bv, const float* __restrict__ bs,
               float* __restrict__ q, unsigned short* __restrict__ kv,
               float* __restrict__ outskip) {
    constexpr int NKS  = (K + 31) / 32;
    constexpr int OUTT = 4 * OUT;
    constexpr int NCT  = OUTT / 16;

    const int t    = threadIdx.x;
    const int lane = t & 63;
    const int wv   = t >> 6;
    const int g    = lane >> 4;
    const int ln   = lane & 15;
    const int rowbase = (blockIdx.x * 4 + wv) * 32;
    if (rowbase >= NN) return;    // no barriers in this kernel

    union F8 { short8v v; unsigned short s[8]; uint4 u4; };

    // ---- load + split A fragments: 2 row-tiles of 16, K along lane>>4 ----
    F8 ahi[2][NKS], alo[2][NKS];
#pragma unroll
    for (int rt = 0; rt < 2; ++rt) {
        int r = rowbase + rt * 16 + ln;
        if (r >= NN) r = NN - 1;                 // stores are guarded
        const float* rowp = x + (size_t)r * K;
#pragma unroll
        for (int ks = 0; ks < NKS; ++ks) {
            const int k0 = ks * 32 + g * 8;
            float xv[8];
            if (k0 + 8 <= K) {
                float4 p0 = *(const float4*)(rowp + k0);
                float4 p1 = *(const float4*)(rowp + k0 + 4);
                xv[0] = p0.x; xv[1] = p0.y; xv[2] = p0.z; xv[3] = p0.w;
                xv[4] = p1.x; xv[5] = p1.y; xv[6] = p1.z; xv[7] = p1.w;
            } else {
#pragma unroll
                for (int j = 0; j < 8; ++j) xv[j] = 0.f;   // K=8 zero-pad
            }
#pragma unroll
            for (int j = 0; j < 8; ++j) {
                unsigned short h = f32_to_bf16_rne(xv[j]);
                ahi[rt][ks].s[j] = h;
                alo[rt][ks].s[j] = f32_to_bf16_rne(xv[j] - bf16_to_f32(h));
            }
        }
    }

#pragma unroll 1
    for (int ct = 0; ct < NCT; ++ct) {
        F8 bhi[NKS], blo[NKS];
        const unsigned short* wp = wsp + (size_t)(ct * NKS) * 1024 + lane * 8;
#pragma unroll
        for (int ks = 0; ks < NKS; ++ks) {
            bhi[ks].u4 = *(const uint4*)(wp + ks * 1024);
            blo[ks].u4 = *(const uint4*)(wp + ks * 1024 + 512);
        }

        const int cb  = ct * 16;
        const int mat = cb / OUT;                // wave-uniform
        const int cm  = (cb % OUT) + ln;
        const float* B = (mat == 0) ? bq : (mat == 1) ? bk : (mat == 2) ? bv : bs;
        const float bias = B[cm];
        float4v acc0 = {bias, bias, bias, bias};
        float4v acc1 = {bias, bias, bias, bias};
#pragma unroll
        for (int ks = 0; ks < NKS; ++ks) {
            acc0 = __builtin_amdgcn_mfma_f32_16x16x32_bf16(ahi[0][ks].v, blo[ks].v, acc0, 0, 0, 0);
            acc0 = __builtin_amdgcn_mfma_f32_16x16x32_bf16(alo[0][ks].v, bhi[ks].v, acc0, 0, 0, 0);
            acc0 = __builtin_amdgcn_mfma_f32_16x16x32_bf16(ahi[0][ks].v, bhi[ks].v, acc0, 0, 0, 0);
            acc1 = __builtin_amdgcn_mfma_f32_16x16x32_bf16(ahi[1][ks].v, blo[ks].v, acc1, 0, 0, 0);
            acc1 = __builtin_amdgcn_mfma_f32_16x16x32_bf16(alo[1][ks].v, bhi[ks].v, acc1, 0, 0, 0);
            acc1 = __builtin_amdgcn_mfma_f32_16x16x32_bf16(ahi[1][ks].v, bhi[ks].v, acc1, 0, 0, 0);
        }

        // ---- epilogue: D row = (lane>>4)*4 + reg, col = lane&15 (HW-verified) ----
        if (mat == 0 || mat == 3) {
            float* dst = (mat == 0) ? q : outskip;
#pragma unroll
            for (int rt = 0; rt < 2; ++rt) {
                float4v a = rt ? acc1 : acc0;
#pragma unroll
                for (int reg = 0; reg < 4; ++reg) {
                    int node = rowbase + rt * 16 + g * 4 + reg;
                    if (node < NN)
                        dst[(size_t)node * OUT + cm] = a[reg];
                }
            }
        } else {
            // interleaved kv: channel c -> (c>>2)*8 + (c&3) + (k?0:4)
            const int base = (mat == 1) ? 0 : 4;
            const int kvoff = ((cm >> 2) * 8) + (cm & 3) + base;
#pragma unroll
            for (int rt = 0; rt < 2; ++rt) {
                float4v a = rt ? acc1 : acc0;
#pragma unroll
                for (int reg = 0; reg < 4; ++reg) {
                    int node = rowbase + rt * 16 + g * 4 + reg;
                    float f = a[reg];
                    float other = __shfl_xor(f, 1);  // pair adjacent columns
                    if (node < NN && !(ln & 1)) {
                        unsigned lo16 = __half_as_ushort(__float2half_rn(f));
                        unsigned hi16 = __half_as_ushort(__float2half_rn(other));
                        *(unsigned*)(kv + (size_t)node * (2 * OUT) + kvoff)
                            = lo16 | (hi16 << 16);
                    }
                }
            }
        }
    }
}

// ---------------- deterministic radix partition by dst>>8 ----------------
__global__ __launch_bounds__(256)
void bin_count(const int* __restrict__ ei, int* __restrict__ hist) {
    __shared__ int h[NBUCK];
    const int t = threadIdx.x;
    for (int i = t; i < NBUCK; i += 256) h[i] = 0;
    __syncthreads();
    int e0 = blockIdx.x * EPB;
    int e1 = e0 + EPB < NE ? e0 + EPB : NE;
    for (int i = e0 + t; i < e1; i += 256)
        atomicAdd(&h[ei[NE + i] >> 8], 1);
    __syncthreads();
    for (int i = t; i < NBUCK; i += 256)
        hist[(size_t)i * NBLK + blockIdx.x] = h[i];
}

__global__ __launch_bounds__(SCAN_T)
void gscan1(int* __restrict__ a, int* __restrict__ bsums) {
    __shared__ int lds[SCAN_T];
    int t = threadIdx.x;
    int base = blockIdx.x * SCAN_E + t * 4;
    int vals[4];
    int s = 0;
#pragma unroll
    for (int j = 0; j < 4; ++j) {
        int idx = base + j;
        vals[j] = (idx < HISTN) ? a[idx] : 0;
        s += vals[j];
    }
    lds[t] = s;
    __syncthreads();
    for (int off = 1; off < SCAN_T; off <<= 1) {
        int xx = (t >= off) ? lds[t - off] : 0;
        __syncthreads();
        lds[t] += xx;
        __syncthreads();
    }
    int run = (t > 0) ? lds[t - 1] : 0;
    if (t == SCAN_T - 1) bsums[blockIdx.x] = lds[t];
#pragma unroll
    for (int j = 0; j < 4; ++j) {
        int idx = base + j;
        if (idx < HISTN) a[idx] = run;
        run += vals[j];
    }
}

__global__ __launch_bounds__(256)
void gscan2(int* __restrict__ bsums) {
    __shared__ int lds[256];
    int t = threadIdx.x;
    lds[t] = (t < GS_NB) ? bsums[t] : 0;
    __syncthreads();
    for (int off = 1; off < 256; off <<= 1) {
        int xx = (t >= off) ? lds[t - off] : 0;
        __syncthreads();
        lds[t] += xx;
        __syncthreads();
    }
    if (t < GS_NB) bsums[t] = (t > 0) ? lds[t - 1] : 0;
}

__global__ __launch_bounds__(256)
void gscan3(int* __restrict__ a, const int* __restrict__ bsums,
            int* __restrict__ bstart) {
    int i = blockIdx.x * 256 + threadIdx.x;
    if (i < HISTN) {
        int v = a[i] + bsums[i / SCAN_E];
        a[i] = v;
        if (i % NBLK == 0) bstart[i / NBLK] = v;
    }
    if (i == 0) bstart[NBUCK] = NE;
}

__global__ __launch_bounds__(256)
void bin_scatter(const int* __restrict__ ei, const int* __restrict__ hist,
                 unsigned* __restrict__ ebuf) {
    __shared__ int off[NBUCK];
    const int t = threadIdx.x;
    for (int i = t; i < NBUCK; i += 256)
        off[i] = hist[(size_t)i * NBLK + blockIdx.x];
    __syncthreads();
    int e0 = blockIdx.x * EPB;
    int e1 = e0 + EPB < NE ? e0 + EPB : NE;
    for (int i = e0 + t; i < e1; i += 256) {
        int src = ei[i];
        int dst = ei[NE + i];
        int b = dst >> 8;
        int p = atomicAdd(&off[b], 1);
        ebuf[p] = ((unsigned)(dst & 255) << 17) | (unsigned)src;
    }
}

// sort each bucket in LDS, write CSR segment AND the per-dst offsets
// (offsets[d] = bstart[b] + within-bucket exclusive prefix — replaces the
//  former bucket_hist + 3-stage dst scan entirely)
__global__ __launch_bounds__(256)
void csr_write(const int* __restrict__ bstart,
               const unsigned* __restrict__ ebuf,
               int* __restrict__ offsets,
               int* __restrict__ sorted_src) {
    __shared__ int h[256];
    __shared__ int pre[256];
    __shared__ int posi[256];
    __shared__ unsigned srt[BCAP];
    const int b = blockIdx.x;
    const int t = threadIdx.x;
    h[t] = 0;
    __syncthreads();
    int beg = bstart[b];
    int cnt = bstart[b + 1] - beg;
    cnt = cnt < BCAP ? cnt : BCAP;
    const unsigned* buf = ebuf + beg;
    for (int i = t; i < cnt; i += 256)
        atomicAdd(&h[buf[i] >> 17], 1);
    __syncthreads();
    int v = h[t];
    pre[t] = v;
    __syncthreads();
    for (int off = 1; off < 256; off <<= 1) {
        int xx = (t >= off) ? pre[t - off] : 0;
        __syncthreads();
        pre[t] += xx;
        __syncthreads();
    }
    int excl = pre[t] - v;      // exclusive prefix within bucket
    posi[t] = excl;
    int d = b * 256 + t;
    if (d < NN) offsets[d] = beg + excl;
    if (b == NBUCK - 1 && t == 0) offsets[NN] = NE;
    __syncthreads();
    for (int i = t; i < cnt; i += 256) {
        unsigned u = buf[i];
        int dl = u >> 17;
        int p = atomicAdd(&posi[dl], 1);
        srt[p] = u & 0x1FFFFu;
    }
    __syncthreads();
    for (int i = t; i < cnt; i += 256)
        sorted_src[beg + i] = (int)srt[i];
}

// ---- 16-lane row sum via DPP rotates (VALU pipe, no LDS) ----
__device__ __forceinline__ float row16_sum(float x) {
    int y;
    y = __builtin_amdgcn_update_dpp(0, __float_as_int(x), 0x121, 0xF, 0xF, true); x += __int_as_float(y);
    y = __builtin_amdgcn_update_dpp(0, __float_as_int(x), 0x122, 0xF, 0xF, true); x += __int_as_float(y);
    y = __builtin_amdgcn_update_dpp(0, __float_as_int(x), 0x124, 0xF, 0xF, true); x += __int_as_float(y);
    y = __builtin_amdgcn_update_dpp(0, __float_as_int(x), 0x128, 0xF, 0xF, true); x += __int_as_float(y);
    return x;
}

// dot-accumulate with f16 source: mix-fma friendly (exact f16->f32 in-op)
__device__ __forceinline__ float mix2(float acc, unsigned u, float q0, float q1) {
    __half2 h = *(__half2*)&u;
    acc = fmaf(__half2float(h.x), q0, acc);
    return fmaf(__half2float(h.y), q1, acc);
}
// a += w * v for a packed f16 pair (mix-fma friendly)
__device__ __forceinline__ void vmix2(float& a0, float& a1, unsigned u, float w) {
    __half2 h = *(__half2*)&u;
    a0 = fmaf(__half2float(h.x), w, a0);
    a1 = fmaf(__half2float(h.y), w, a1);
}

// ---------------- fused attention gather: batched online softmax ----------------
// block = 128 (2 dsts) to minimize degree-tail wave-slot holding.
// 16-lane groups, 4 edges per batch per group; ONE softmax update per batch.
template<int C, bool RELU>
__global__ __launch_bounds__(128)
void attn_gather(const int* __restrict__ offsets,
                 const int* __restrict__ sorted_src,
                 const float* __restrict__ q,
                 const unsigned short* __restrict__ kv,
                 float* __restrict__ out, float scale) {
    const int wid  = (int)((blockIdx.x * blockDim.x + threadIdx.x) >> 6);
    const int lane = threadIdx.x & 63;
    if (wid >= NN) return;
    const int grp = lane >> 4;
    const int ch  = (lane & 15) * 4;
    constexpr bool P2 = (C > 64);
    const bool hi = P2 && (ch + 64 < C);

    const int beg = offsets[wid], end = offsets[wid + 1];

    const float sl = scale * 1.44269504f;   // fold scale + log2(e) into q
    float4 qv0 = *(const float4*)(q + (size_t)wid * C + ch);
    qv0.x *= sl; qv0.y *= sl; qv0.z *= sl; qv0.w *= sl;
    float4 qv1 = make_float4(0.f, 0.f, 0.f, 0.f);
    if (hi) {
        qv1 = *(const float4*)(q + (size_t)wid * C + ch + 64);
        qv1.x *= sl; qv1.y *= sl; qv1.z *= sl; qv1.w *= sl;
    }

    float m = -FLT_MAX, l = 0.f;
    float4 a0 = make_float4(0.f, 0.f, 0.f, 0.f);
    float4 a1 = make_float4(0.f, 0.f, 0.f, 0.f);

    const unsigned short* kvch = kv + 2 * ch;
    const uint4 zz = make_uint4(0, 0, 0, 0);

    int i = beg + grp;
    while (i < end) {
        // ---- load batch of 4 edges (this group's stride-4 chain) ----
        uint4 t0[4], t1[4];
#pragma unroll
        for (int j = 0; j < 4; ++j) {
            t0[j] = zz; t1[j] = zz;
            int idx = i + 4 * j;
            if (idx < end) {
                const unsigned short* row = kvch + (size_t)sorted_src[idx] * (2 * C);
                t0[j] = *(const uint4*)(row);
                if (hi) t1[j] = *(const uint4*)(row + 128);
            }
        }
        // ---- 4 independent scores (ILP, mix-fma) ----
        float s[4];
#pragma unroll
        for (int j = 0; j < 4; ++j) {
            float part = 0.f;
            part = mix2(part, t0[j].x, qv0.x, qv0.y);
            part = mix2(part, t0[j].y, qv0.z, qv0.w);
            if (P2) {
                part = mix2(part, t1[j].x, qv1.x, qv1.y);
                part = mix2(part, t1[j].y, qv1.z, qv1.w);
            }
            part = row16_sum(part);                 // log2-domain score
            s[j] = (i + 4 * j < end) ? part : -FLT_MAX;
        }
        // ---- ONE combined softmax update for the batch ----
        float mn = fmaxf(m, fmaxf(fmaxf(s[0], s[1]), fmaxf(s[2], s[3])));
        float al = __builtin_amdgcn_exp2f(m - mn);
        float w[4];
#pragma unroll
        for (int j = 0; j < 4; ++j)
            w[j] = __builtin_amdgcn_exp2f(s[j] - mn);   // -FLT_MAX-mn -> 0
        l = l * al + ((w[0] + w[1]) + (w[2] + w[3]));
        a0.x *= al; a0.y *= al; a0.z *= al; a0.w *= al;
        if (P2) { a1.x *= al; a1.y *= al; a1.z *= al; a1.w *= al; }
#pragma unroll
        for (int j = 0; j < 4; ++j) {
            vmix2(a0.x, a0.y, t0[j].z, w[j]);
            vmix2(a0.z, a0.w, t0[j].w, w[j]);
            if (P2) {
                vmix2(a1.x, a1.y, t1[j].z, w[j]);
                vmix2(a1.z, a1.w, t1[j].w, w[j]);
            }
        }
        m = mn;
        i += 16;
    }

    // merge the 4 groups: butterfly over lane-xor 16, 32
#pragma unroll
    for (int d = 16; d <= 32; d <<= 1) {
        float mo = __shfl_xor(m, d);
        float lo = __shfl_xor(l, d);
        float4 ao0, ao1;
        ao0.x = __shfl_xor(a0.x, d); ao0.y = __shfl_xor(a0.y, d);
        ao0.z = __shfl_xor(a0.z, d); ao0.w = __shfl_xor(a0.w, d);
        if (P2) {
            ao1.x = __shfl_xor(a1.x, d); ao1.y = __shfl_xor(a1.y, d);
            ao1.z = __shfl_xor(a1.z, d); ao1.w = __shfl_xor(a1.w, d);
        }
        float mn = fmaxf(m, mo);
        float e1 = (l  > 0.f) ? __builtin_amdgcn_exp2f(m  - mn) : 0.f;
        float e2 = (lo > 0.f) ? __builtin_amdgcn_exp2f(mo - mn) : 0.f;
        l = l * e1 + lo * e2;
        a0.x = a0.x * e1 + ao0.x * e2; a0.y = a0.y * e1 + ao0.y * e2;
        a0.z = a0.z * e1 + ao0.z * e2; a0.w = a0.w * e1 + ao0.w * e2;
        if (P2) {
            a1.x = a1.x * e1 + ao1.x * e2; a1.y = a1.y * e1 + ao1.y * e2;
            a1.z = a1.z * e1 + ao1.z * e2; a1.w = a1.w * e1 + ao1.w * e2;
        }
        m = mn;
    }

    if (lane < 16) {
        float inv = (l > 0.f) ? 1.f / l : 0.f;
        size_t o = (size_t)wid * C + ch;
        float4 sk = *(const float4*)(out + o);
        float4 r;
        r.x = sk.x + a0.x * inv; r.y = sk.y + a0.y * inv;
        r.z = sk.z + a0.z * inv; r.w = sk.w + a0.w * inv;
        if (RELU) {
            r.x = fmaxf(r.x, 0.f); r.y = fmaxf(r.y, 0.f);
            r.z = fmaxf(r.z, 0.f); r.w = fmaxf(r.w, 0.f);
        }
        *(float4*)(out + o) = r;
        if (hi) {
            float4 sk1 = *(const float4*)(out + o + 64);
            float4 r1;
            r1.x = sk1.x + a1.x * inv; r1.y = sk1.y + a1.y * inv;
            r1.z = sk1.z + a1.z * inv; r1.w = sk1.w + a1.w * inv;
            if (RELU) {
                r1.x = fmaxf(r1.x, 0.f); r1.y = fmaxf(r1.y, 0.f);
                r1.z = fmaxf(r1.z, 0.f); r1.w = fmaxf(r1.w, 0.f);
            }
            *(float4*)(out + o + 64) = r1;
        }
    }
}

// ---------------- host side ----------------
template<int K, int OUT, bool RELU>
static void run_layer(const float* xin, const unsigned short* wsp,
                      const float* const* Wb,
                      const int* offsets, const int* sorted_src,
                      float* q, unsigned short* kv,
                      float* out, hipStream_t stream) {
    gemm_qkvs<K, OUT><<<(NN + 127) / 128, 256, 0, stream>>>(
        xin, wsp, Wb[1], Wb[3], Wb[5], Wb[7], q, kv, out);

    float scale = 1.0f / sqrtf((float)OUT);
    attn_gather<OUT, RELU><<<(NN + 1) / 2, 128, 0, stream>>>(
        offsets, sorted_src, q, kv, out, scale);
}

extern "C" void kernel_launch(void* const* d_in, const int* in_sizes, int n_in,
                              void* d_out, int out_size, void* d_ws, size_t ws_size,
                              hipStream_t stream) {
    const float* x  = (const float*)d_in[0];
    const int*   ei = (const int*)d_in[1];
    const float* Wb0[8], *Wb1[8], *Wb2[8];
    for (int i = 0; i < 8; ++i) {
        Wb0[i] = (const float*)d_in[2 + i];
        Wb1[i] = (const float*)d_in[10 + i];
        Wb2[i] = (const float*)d_in[18 + i];
    }
    float* out = (float*)d_out;

    char* ws = (char*)d_ws;
    const size_t CMAX = 112;
    size_t off = 0;
    float*          q  = (float*)(ws + off);          off += (size_t)NN * CMAX * 4;
    unsigned short* kv = (unsigned short*)(ws + off); off += (size_t)NN * 2 * CMAX * 2;
    float* h0          = (float*)(ws + off);          off += (size_t)NN * 64 * 4;
    float* h1          = (float*)(ws + off);          off += (size_t)NN * 64 * 4;
    int*   sorted_src  = (int*)(ws + off);            off += (size_t)NE * 4;
    int*   offsets     = (int*)(ws + off);            off += (size_t)(NN + 1) * 4;
    int*   hist        = (int*)(ws + off);            off += (size_t)HISTN * 4;
    int*   gsums       = (int*)(ws + off);            off += (size_t)GS_NB * 4;
    int*   bstart      = (int*)(ws + off);            off += (size_t)(NBUCK + 1) * 4;
    unsigned* ebuf     = (unsigned*)(ws + off);       off += (size_t)NE * 4;
    (void)ws_size; (void)in_sizes; (void)n_in; (void)out_size;

    // ---- build CSR once: radix partition + per-bucket LDS sort (6 launches) ----
    bin_count<<<NBLK, 256, 0, stream>>>(ei, hist);
    gscan1<<<GS_NB, SCAN_T, 0, stream>>>(hist, gsums);
    gscan2<<<1, 256, 0, stream>>>(gsums);
    gscan3<<<(HISTN + 255) / 256, 256, 0, stream>>>(hist, gsums, bstart);
    bin_scatter<<<NBLK, 256, 0, stream>>>(ei, hist, ebuf);
    csr_write<<<NBUCK, 256, 0, stream>>>(bstart, ebuf, offsets, sorted_src);

    // ---- W pre-split (aliased into ebuf; dead after csr_write, stream-ordered) ----
    unsigned short* wspbase =
        (unsigned short*)(((uintptr_t)ebuf + 255) & ~(uintptr_t)255);
    unsigned short* wsp0 = wspbase;                  // 16 ct * 1 ks * 1024
    unsigned short* wsp1 = wsp0 + 16 * 1 * 1024;     // 16 ct * 2 ks * 1024
    unsigned short* wsp2 = wsp1 + 16 * 2 * 1024;     // 28 ct * 2 ks * 1024
    prep_w_all<<<(PREP_NT + 255) / 256, 256, 0, stream>>>(
        Wb0[0], Wb0[2], Wb0[4], Wb0[6],
        Wb1[0], Wb1[2], Wb1[4], Wb1[6],
        Wb2[0], Wb2[2], Wb2[4], Wb2[6],
        wsp0, wsp1, wsp2);

    run_layer<8,  64, true >(x,  wsp0, Wb0, offsets, sorted_src, q, kv, h0,  stream);
    run_layer<64, 64, true >(h0, wsp1, Wb1, offsets, sorted_src, q, kv, h1,  stream);
    run_layer<64, 112, false>(h1, wsp2, Wb2, offsets, sorted_src, q, kv, out, stream);
}